// Round 1
// baseline (935.709 us; speedup 1.0000x reference)
//
#include <hip/hip_runtime.h>
#include <hip/hip_bf16.h>
#include <math.h>

#define B_ 2
#define S_ 2048
#define D_ 1024
#define H_ 16
#define HD_ 64
#define R_ 128
#define NBLK 32
#define TOPK_ 4
#define BS_ (B_*S_)

// ---------------- RoPE tables: cos/sin [S, HD] fp32 ----------------
__global__ void rope_tables_k(float* __restrict__ cosT, float* __restrict__ sinT) {
    int idx = blockIdx.x*256 + threadIdx.x;
    if (idx >= S_*HD_) return;
    int s  = idx >> 6;
    int hd = idx & 63;
    int j = (hd < HD_/2) ? hd : hd - HD_/2;
    float inv = powf(100000.0f, -((float)(2*j) / (float)HD_));
    float fr = (float)s * inv;
    cosT[idx] = cosf(fr);
    sinT[idx] = sinf(fr);
}

// ---------------- C[M,N] = A[M,K] @ B[N,K]^T, fp32, tiles 128x128x8 ----------------
__global__ __launch_bounds__(256) void gemm_bt_k(const float* __restrict__ A,
        const float* __restrict__ Bm, float* __restrict__ C, int M, int N, int K) {
    constexpr int BM=128, BN=128, BK=8;
    __shared__ float As[BK][BM];
    __shared__ float Bs[BK][BN];
    const int bm = blockIdx.y * BM;
    const int bn = blockIdx.x * BN;
    const int tid = threadIdx.x;
    const int tm = (tid >> 4) << 3;   // 0..120
    const int tn = (tid & 15) << 3;   // 0..120
    const int lr = tid >> 1;          // 0..127
    const int lc = (tid & 1) << 2;    // 0 or 4
    float acc[8][8] = {};
    for (int k0 = 0; k0 < K; k0 += BK) {
        float4 av = *(const float4*)&A [(size_t)(bm+lr)*K + k0 + lc];
        float4 bv = *(const float4*)&Bm[(size_t)(bn+lr)*K + k0 + lc];
        __syncthreads();
        As[lc+0][lr]=av.x; As[lc+1][lr]=av.y; As[lc+2][lr]=av.z; As[lc+3][lr]=av.w;
        Bs[lc+0][lr]=bv.x; Bs[lc+1][lr]=bv.y; Bs[lc+2][lr]=bv.z; Bs[lc+3][lr]=bv.w;
        __syncthreads();
        #pragma unroll
        for (int kk=0; kk<BK; ++kk) {
            float4 a0 = *(const float4*)&As[kk][tm];
            float4 a1 = *(const float4*)&As[kk][tm+4];
            float4 b0 = *(const float4*)&Bs[kk][tn];
            float4 b1 = *(const float4*)&Bs[kk][tn+4];
            float a[8] = {a0.x,a0.y,a0.z,a0.w,a1.x,a1.y,a1.z,a1.w};
            float b[8] = {b0.x,b0.y,b0.z,b0.w,b1.x,b1.y,b1.z,b1.w};
            #pragma unroll
            for (int i=0;i<8;i++) {
                #pragma unroll
                for (int j=0;j<8;j++)
                    acc[i][j] = fmaf(a[i], b[j], acc[i][j]);
            }
        }
    }
    #pragma unroll
    for (int i=0;i<8;i++) {
        float4 c0 = {acc[i][0],acc[i][1],acc[i][2],acc[i][3]};
        float4 c1 = {acc[i][4],acc[i][5],acc[i][6],acc[i][7]};
        *(float4*)&C[(size_t)(bm+tm+i)*N + bn+tn  ] = c0;
        *(float4*)&C[(size_t)(bm+tm+i)*N + bn+tn+4] = c1;
    }
}

// ---------------- block scores: one wg per (b, kb) ----------------
__global__ __launch_bounds__(256) void block_scores_k(const float* __restrict__ x,
        const float* __restrict__ wsc, float* __restrict__ scores) {
    int b  = blockIdx.x / NBLK;
    int kb = blockIdx.x % NBLK;
    const float* xb = x + ((size_t)b*S_ + (size_t)kb*64)*D_;
    float p = 0.0f;
    for (int i = threadIdx.x; i < 64*D_; i += 256)
        p += xb[i] * wsc[i & (D_-1)];
    __shared__ float red[256];
    red[threadIdx.x] = p;
    __syncthreads();
    for (int off=128; off>0; off>>=1) {
        if (threadIdx.x < off) red[threadIdx.x] += red[threadIdx.x+off];
        __syncthreads();
    }
    if (threadIdx.x == 0) scores[b*NBLK+kb] = red[0] * (1.0f/64.0f);
}

// ---------------- top-4 per batch (strict > == lowest index on ties) ----------------
__global__ void topk_sel_k(const float* __restrict__ scores, int* __restrict__ sel) {
    int b = threadIdx.x;
    if (b >= B_) return;
    float sc[NBLK];
    for (int i=0;i<NBLK;i++) sc[i] = scores[b*NBLK+i];
    int ch[TOPK_];
    for (int j=0;j<TOPK_;j++) {
        float best = -INFINITY; int bi = 0;
        for (int i=0;i<NBLK;i++)
            if (sc[i] > best) { best = sc[i]; bi = i; }
        ch[j] = bi;
        sc[bi] = -INFINITY;
    }
    for (int a=0;a<TOPK_;a++)
        for (int c=a+1;c<TOPK_;c++)
            if (ch[c] < ch[a]) { int t=ch[a]; ch[a]=ch[c]; ch[c]=t; }
    for (int j=0;j<TOPK_;j++) sel[b*TOPK_+j] = ch[j];
}

// ---------------- RoPE + [B,S,H,HD] -> [B,H,S,HD] reorg for q,k; transpose v ----------------
__global__ __launch_bounds__(256) void reorg_k(const float* __restrict__ qlin,
        const float* __restrict__ kv, const float* __restrict__ cosT,
        const float* __restrict__ sinT, float* __restrict__ qr,
        float* __restrict__ kr, float* __restrict__ vr) {
    int idx = blockIdx.x*256 + threadIdx.x;   // [B,H,S,HD] linear
    int hd = idx & 63;
    int s  = (idx >> 6) & (S_-1);
    int h  = (idx >> 17) & (H_-1);
    int b  = idx >> 21;
    float c  = cosT[(s<<6)+hd];
    float sn = sinT[(s<<6)+hd];
    size_t rowq = (size_t)(b*S_+s)*D_ + h*HD_;
    float qv = qlin[rowq + hd];
    float qrot = (hd < 32) ? -qlin[rowq + hd + 32] : qlin[rowq + hd - 32];
    qr[idx] = qv*c + qrot*sn;
    size_t rowk = (size_t)(b*S_+s)*(2*D_) + h*HD_;
    float kvv = kv[rowk + hd];
    float krot = (hd < 32) ? -kv[rowk + hd + 32] : kv[rowk + hd - 32];
    kr[idx] = kvv*c + krot*sn;
    vr[idx] = kv[rowk + D_ + hd];
}

// ---------------- vmean[b,h,hd] = mean_s v (for zero-allowed-key rows) ----------------
__global__ __launch_bounds__(64) void vmean_k(const float* __restrict__ vr, float* __restrict__ vm) {
    int bh = blockIdx.x;
    int hd = threadIdx.x;
    const float* vp = vr + (size_t)bh*S_*HD_ + hd;
    float s = 0.0f;
    for (int i=0;i<S_;i++) s += vp[(size_t)i*HD_];
    vm[bh*HD_+hd] = s * (1.0f/(float)S_);
}

// ---------------- block-sparse causal attention; wg = (b,h,qblock), 64 thr = 64 queries ----------------
__global__ __launch_bounds__(64) void attn_k(const float* __restrict__ qr,
        const float* __restrict__ kr, const float* __restrict__ vr,
        const int* __restrict__ sel, const float* __restrict__ vmeanp,
        float* __restrict__ attno) {
    const int qb  = blockIdx.x & (NBLK-1);
    const int bh  = blockIdx.x >> 5;
    const int b   = bh >> 4;
    const int h   = bh & 15;
    const int tid = threadIdx.x;
    const int qpos = qb*64 + tid;

    __shared__ float Ks[64][68];   // padded: 68*4B = 272B row, 16B aligned
    __shared__ float Vs[64][68];
    __shared__ float Ss[64][65];   // per-thread score row

    int selb[4];
    #pragma unroll
    for (int j=0;j<4;j++) selb[j] = sel[b*TOPK_+j];
    bool diag = (selb[0]==qb)||(selb[1]==qb)||(selb[2]==qb)||(selb[3]==qb);

    const float* qrow = qr + ((size_t)bh*S_ + qpos)*HD_;
    float q[64];
    #pragma unroll
    for (int d=0;d<64;d++) q[d] = qrow[d];
    float o[64];
    #pragma unroll
    for (int d=0;d<64;d++) o[d] = 0.0f;
    float m = -INFINITY, l = 0.0f;
    int nproc = 0;

    for (int j=0; j<5; ++j) {               // 4 selected + possibly the diagonal
        int kb; bool isdiag;
        if (j < 4) { kb = selb[j]; isdiag = false; if (kb >= qb) continue; }
        else       { if (!diag) continue; kb = qb; isdiag = true; }
        nproc++;
        const float* kbase = kr + ((size_t)bh*S_ + (size_t)kb*64)*HD_;
        const float* vbase = vr + ((size_t)bh*S_ + (size_t)kb*64)*HD_;
        __syncthreads();
        #pragma unroll 4
        for (int i=0;i<64;i++) {
            Ks[i][tid] = kbase[i*HD_ + tid];
            Vs[i][tid] = vbase[i*HD_ + tid];
        }
        __syncthreads();
        float bmax = -INFINITY;
        for (int i=0;i<64;i++) {
            float scv;
            if (isdiag && i > tid) {
                scv = -1e30f;                 // masked; exp underflows to exactly 0
            } else {
                float acc = 0.0f;
                #pragma unroll
                for (int d4=0; d4<16; ++d4) {
                    float4 k4 = *(const float4*)&Ks[i][d4*4];
                    acc = fmaf(q[d4*4+0], k4.x, acc);
                    acc = fmaf(q[d4*4+1], k4.y, acc);
                    acc = fmaf(q[d4*4+2], k4.z, acc);
                    acc = fmaf(q[d4*4+3], k4.w, acc);
                }
                scv = acc * 0.125f;           // 1/sqrt(64)
            }
            Ss[tid][i] = scv;
            bmax = fmaxf(bmax, scv);
        }
        float mnew = fmaxf(m, bmax);
        float cf = expf(m - mnew);
        l *= cf;
        #pragma unroll
        for (int d=0;d<64;d++) o[d] *= cf;
        for (int i=0;i<64;i++) {
            float p = expf(Ss[tid][i] - mnew);
            l += p;
            #pragma unroll
            for (int d4=0; d4<16; ++d4) {
                float4 v4 = *(const float4*)&Vs[i][d4*4];
                o[d4*4+0] = fmaf(p, v4.x, o[d4*4+0]);
                o[d4*4+1] = fmaf(p, v4.y, o[d4*4+1]);
                o[d4*4+2] = fmaf(p, v4.z, o[d4*4+2]);
                o[d4*4+3] = fmaf(p, v4.w, o[d4*4+3]);
            }
        }
        m = mnew;
    }

    float* op = attno + ((size_t)(b*S_) + qpos)*D_ + h*HD_;
    if (nproc == 0) {
        // softmax over all -1e30 == uniform 1/S over ALL keys -> mean of v
        const float* vm = vmeanp + bh*HD_;
        #pragma unroll
        for (int d=0;d<64;d++) op[d] = vm[d];
    } else {
        float inv_l = 1.0f / l;
        #pragma unroll
        for (int d=0;d<64;d++) op[d] = o[d] * inv_l;
    }
}

extern "C" void kernel_launch(void* const* d_in, const int* in_sizes, int n_in,
                              void* d_out, int out_size, void* d_ws, size_t ws_size,
                              hipStream_t stream) {
    (void)in_sizes; (void)n_in; (void)out_size; (void)ws_size;
    const float* x     = (const float*)d_in[0];
    const float* w_q   = (const float*)d_in[1];
    const float* w_kvd = (const float*)d_in[2];
    const float* w_kvu = (const float*)d_in[3];
    const float* w_o   = (const float*)d_in[4];
    const float* w_sc  = (const float*)d_in[5];
    float* out = (float*)d_out;

    char* p = (char*)d_ws;
    auto alloc = [&](size_t bytes) -> void* {
        void* r = (void*)p;
        p += (bytes + 255) & ~(size_t)255;
        return r;
    };
    float* cosT   = (float*)alloc((size_t)S_*HD_*4);
    float* sinT   = (float*)alloc((size_t)S_*HD_*4);
    float* qlin   = (float*)alloc((size_t)BS_*D_*4);      // reused as attno
    float* kv     = (float*)alloc((size_t)BS_*2*D_*4);
    float* latent = (float*)alloc((size_t)BS_*R_*4);
    float* qr     = (float*)alloc((size_t)BS_*D_*4);
    float* kr     = (float*)alloc((size_t)BS_*D_*4);
    float* vr     = (float*)alloc((size_t)BS_*D_*4);
    float* scores = (float*)alloc((size_t)B_*NBLK*4);
    int*   sel    = (int*)  alloc((size_t)B_*TOPK_*4);
    float* vmeanp = (float*)alloc((size_t)B_*H_*HD_*4);
    float* attno  = qlin;   // qlin dead after reorg_k

    rope_tables_k<<<(S_*HD_+255)/256, 256, 0, stream>>>(cosT, sinT);
    gemm_bt_k<<<dim3(D_/128,   BS_/128), 256, 0, stream>>>(x,      w_q,   qlin,   BS_, D_,   D_);
    gemm_bt_k<<<dim3(R_/128,   BS_/128), 256, 0, stream>>>(x,      w_kvd, latent, BS_, R_,   D_);
    gemm_bt_k<<<dim3(2*D_/128, BS_/128), 256, 0, stream>>>(latent, w_kvu, kv,     BS_, 2*D_, R_);
    block_scores_k<<<B_*NBLK, 256, 0, stream>>>(x, w_sc, scores);
    topk_sel_k<<<1, 64, 0, stream>>>(scores, sel);
    reorg_k<<<(B_*H_*S_*HD_)/256, 256, 0, stream>>>(qlin, kv, cosT, sinT, qr, kr, vr);
    vmean_k<<<B_*H_, 64, 0, stream>>>(vr, vmeanp);
    attn_k<<<B_*H_*NBLK, 64, 0, stream>>>(qr, kr, vr, sel, vmeanp, attno);
    gemm_bt_k<<<dim3(D_/128, BS_/128), 256, 0, stream>>>(attno, w_o, out, BS_, D_, D_);
}

// Round 2
// 410.465 us; speedup vs baseline: 2.2796x; 2.2796x over previous
//
#include <hip/hip_runtime.h>
#include <hip/hip_bf16.h>
#include <math.h>

#define B_ 2
#define S_ 2048
#define D_ 1024
#define H_ 16
#define HD_ 64
#define R_ 128
#define NBLK 32
#define TOPK_ 4
#define BS_ (B_*S_)

typedef __attribute__((ext_vector_type(8))) short bf16x8;
typedef __attribute__((ext_vector_type(4))) float f32x4;

__device__ __forceinline__ unsigned short f2bf(float f) {
    unsigned int u = __float_as_uint(f);
    u += 0x7fffu + ((u >> 16) & 1u);
    return (unsigned short)(u >> 16);
}
__device__ __forceinline__ float bf2f(unsigned short h) {
    return __uint_as_float(((unsigned int)h) << 16);
}
__device__ __forceinline__ unsigned int pack2(float a, float b) {
    return (unsigned int)f2bf(a) | ((unsigned int)f2bf(b) << 16);
}
__device__ __forceinline__ void gload_lds16(const void* g, void* l) {
    __builtin_amdgcn_global_load_lds((const __attribute__((address_space(1))) void*)g,
                                     (__attribute__((address_space(3))) void*)l, 16, 0, 0);
}

// ---------------- fp32 -> bf16 convert (8 elems/thread) ----------------
__global__ __launch_bounds__(256) void cvt_bf16_k(const float* __restrict__ in,
        unsigned short* __restrict__ out, int n) {
    int i = (blockIdx.x*256 + threadIdx.x)*8;
    if (i >= n) return;
    float4 a = *(const float4*)&in[i];
    float4 b = *(const float4*)&in[i+4];
    uint4 o;
    o.x = pack2(a.x, a.y);
    o.y = pack2(a.z, a.w);
    o.z = pack2(b.x, b.y);
    o.w = pack2(b.z, b.w);
    *(uint4*)&out[i] = o;
}

// ---------------- RoPE tables ----------------
__global__ void rope_tables_k(float* __restrict__ cosT, float* __restrict__ sinT) {
    int idx = blockIdx.x*256 + threadIdx.x;
    if (idx >= S_*HD_) return;
    int s  = idx >> 6;
    int hd = idx & 63;
    int j = (hd < 32) ? hd : hd - 32;
    float inv = powf(100000.0f, -((float)(2*j) / 64.0f));
    float fr = (float)s * inv;
    cosT[idx] = cosf(fr);
    sinT[idx] = sinf(fr);
}

// ---------------- MFMA GEMM: C[M,N] = A[M,K] @ B[N,K]^T, bf16 in, fp32/bf16 out ----------------
// 128x128 tile, BK=64, 4 waves, global_load_lds(16B) with XOR 16B-slot swizzle
template<bool OUT_BF16>
__global__ __launch_bounds__(256) void gemm_mfma_k(const unsigned short* __restrict__ A,
        const unsigned short* __restrict__ Bm, void* __restrict__ Cv,
        int M, int N, int K) {
    __shared__ unsigned short As[128*64];
    __shared__ unsigned short Bs[128*64];
    const int tid  = threadIdx.x;
    const int wave = tid >> 6, lane = tid & 63;
    const int bm = blockIdx.y << 7, bn = blockIdx.x << 7;
    const int wr = wave >> 1, wc = wave & 1;
    const int srow  = lane >> 3;             // row within 8-row chunk
    const int sslot = (lane & 7) ^ srow;     // inverse-swizzled global 16B slot

    f32x4 acc[4][4];
    #pragma unroll
    for (int m=0;m<4;m++)
        #pragma unroll
        for (int n=0;n<4;n++)
            acc[m][n] = (f32x4){0.f,0.f,0.f,0.f};

    for (int k0 = 0; k0 < K; k0 += 64) {
        __syncthreads();
        #pragma unroll
        for (int it = 0; it < 4; ++it) {
            const int chunk = (it << 2) | wave;       // 0..15
            const int row   = (chunk << 3) | srow;    // 0..127
            gload_lds16(A  + (size_t)(bm + row) * K + k0 + (sslot << 3), &As[chunk << 9]);
            gload_lds16(Bm + (size_t)(bn + row) * K + k0 + (sslot << 3), &Bs[chunk << 9]);
        }
        __syncthreads();
        #pragma unroll
        for (int ks = 0; ks < 2; ++ks) {
            const int swb = ((ks << 2) | (lane >> 4)) ^ (lane & 7);  // swizzled read slot
            bf16x8 af[4], bfr[4];
            #pragma unroll
            for (int m = 0; m < 4; ++m) {
                af[m]  = *(const bf16x8*)&As[(((wr << 6) + (m << 4) + (lane & 15)) << 6) + (swb << 3)];
                bfr[m] = *(const bf16x8*)&Bs[(((wc << 6) + (m << 4) + (lane & 15)) << 6) + (swb << 3)];
            }
            #pragma unroll
            for (int m = 0; m < 4; ++m)
                #pragma unroll
                for (int n = 0; n < 4; ++n)
                    acc[m][n] = __builtin_amdgcn_mfma_f32_16x16x32_bf16(af[m], bfr[n], acc[m][n], 0, 0, 0);
        }
    }
    #pragma unroll
    for (int m = 0; m < 4; ++m) {
        const int r0 = bm + (wr << 6) + (m << 4) + ((lane >> 4) << 2);
        #pragma unroll
        for (int n = 0; n < 4; ++n) {
            const int c = bn + (wc << 6) + (n << 4) + (lane & 15);
            #pragma unroll
            for (int j = 0; j < 4; ++j) {
                if (OUT_BF16) ((unsigned short*)Cv)[(size_t)(r0 + j) * N + c] = f2bf(acc[m][n][j]);
                else          ((float*)Cv)[(size_t)(r0 + j) * N + c] = acc[m][n][j];
            }
        }
    }
}

// ---------------- block scores ----------------
__global__ __launch_bounds__(256) void block_scores_k(const float* __restrict__ x,
        const float* __restrict__ wsc, float* __restrict__ scores) {
    int b  = blockIdx.x / NBLK;
    int kb = blockIdx.x % NBLK;
    const float* xb = x + ((size_t)b*S_ + (size_t)kb*64)*D_;
    float p = 0.0f;
    for (int i = threadIdx.x; i < 64*D_; i += 256)
        p += xb[i] * wsc[i & (D_-1)];
    __shared__ float red[256];
    red[threadIdx.x] = p;
    __syncthreads();
    for (int off=128; off>0; off>>=1) {
        if (threadIdx.x < off) red[threadIdx.x] += red[threadIdx.x+off];
        __syncthreads();
    }
    if (threadIdx.x == 0) scores[b*NBLK+kb] = red[0] * (1.0f/64.0f);
}

// ---------------- top-4 (strict > == lowest index on ties) ----------------
__global__ void topk_sel_k(const float* __restrict__ scores, int* __restrict__ sel) {
    int b = threadIdx.x;
    if (b >= B_) return;
    float sc[NBLK];
    for (int i=0;i<NBLK;i++) sc[i] = scores[b*NBLK+i];
    int ch[TOPK_];
    for (int j=0;j<TOPK_;j++) {
        float best = -INFINITY; int bi = 0;
        for (int i=0;i<NBLK;i++)
            if (sc[i] > best) { best = sc[i]; bi = i; }
        ch[j] = bi;
        sc[bi] = -INFINITY;
    }
    for (int a=0;a<TOPK_;a++)
        for (int c=a+1;c<TOPK_;c++)
            if (ch[c] < ch[a]) { int t=ch[a]; ch[a]=ch[c]; ch[c]=t; }
    for (int j=0;j<TOPK_;j++) sel[b*TOPK_+j] = ch[j];
}

// ---------------- RoPE + reorg: qr fp32, kr/vr bf16, [B,H,S,HD] ----------------
__global__ __launch_bounds__(256) void reorg2_k(const float* __restrict__ qlin,
        const float* __restrict__ kv, const float* __restrict__ cosT,
        const float* __restrict__ sinT, float* __restrict__ qr,
        unsigned short* __restrict__ krb, unsigned short* __restrict__ vrb) {
    int idx = blockIdx.x*256 + threadIdx.x;   // [B,H,S,HD] linear
    int hd = idx & 63;
    int s  = (idx >> 6) & (S_-1);
    int h  = (idx >> 17) & (H_-1);
    int b  = idx >> 21;
    float c  = cosT[(s<<6)+hd];
    float sn = sinT[(s<<6)+hd];
    size_t rowq = (size_t)(b*S_+s)*D_ + h*HD_;
    float qv = qlin[rowq + hd];
    float qrot = (hd < 32) ? -qlin[rowq + hd + 32] : qlin[rowq + hd - 32];
    qr[idx] = qv*c + qrot*sn;
    size_t rowk = (size_t)(b*S_+s)*(2*D_) + h*HD_;
    float kvv = kv[rowk + hd];
    float krot = (hd < 32) ? -kv[rowk + hd + 32] : kv[rowk + hd - 32];
    krb[idx] = f2bf(kvv*c + krot*sn);
    vrb[idx] = f2bf(kv[rowk + D_ + hd]);
}

// ---------------- vmean (for rows with zero allowed keys) ----------------
__global__ __launch_bounds__(256) void vmean_k(const unsigned short* __restrict__ vrb,
        float* __restrict__ vm) {
    int bh = blockIdx.x;
    int hd = threadIdx.x & 63;
    int sc = threadIdx.x >> 6;
    const unsigned short* vp = vrb + (((size_t)bh*S_ + sc*512) << 6) + hd;
    float s = 0.0f;
    for (int i=0;i<512;i++) s += bf2f(vp[(size_t)i*64]);
    __shared__ float red[256];
    red[threadIdx.x] = s;
    __syncthreads();
    if (threadIdx.x < 64)
        vm[bh*64+hd] = (red[hd]+red[hd+64]+red[hd+128]+red[hd+192]) * (1.0f/(float)S_);
}

// ---------------- block-sparse attention: wg=(b,h,qb), 4 waves, 64q x 4 dim-chunks ----------------
__global__ __launch_bounds__(256) void attn_k(const float* __restrict__ qr,
        const unsigned short* __restrict__ krb, const unsigned short* __restrict__ vrb,
        const int* __restrict__ sel, const float* __restrict__ vmeanp,
        unsigned short* __restrict__ attno) {
    const int qb = blockIdx.x & (NBLK-1);
    const int bh = blockIdx.x >> 5;
    const int b  = bh >> 4;
    const int h  = bh & 15;
    const int tid  = threadIdx.x;
    const int lane = tid & 63;
    const int ql = ((tid >> 6) << 4) | (lane & 15);  // query 0..63
    const int dc = lane >> 4;                         // dim chunk 0..3
    const int qpos = (qb << 6) | ql;

    __shared__ unsigned short Ks[64*64];
    __shared__ unsigned short Vs[64*64];

    int selb[4];
    #pragma unroll
    for (int j=0;j<4;j++) selb[j] = sel[(b<<2)+j];
    const bool diag = (selb[0]==qb)|(selb[1]==qb)|(selb[2]==qb)|(selb[3]==qb);

    const float* qp = qr + (((size_t)bh*S_ + qpos) << 6) + (dc << 4);
    float q[16];
    #pragma unroll
    for (int p=0;p<4;p++) {
        float4 t = *(const float4*)&qp[p*4];
        q[4*p]=t.x; q[4*p+1]=t.y; q[4*p+2]=t.z; q[4*p+3]=t.w;
    }
    float o[16];
    #pragma unroll
    for (int d=0;d<16;d++) o[d]=0.f;
    float mrun = -INFINITY, lrun = 0.f;
    int nproc = 0;

    for (int j = 0; j < 5; ++j) {   // block-uniform control flow
        int kb; bool isdiag;
        if (j < 4) { kb = selb[j]; isdiag = false; if (kb >= qb) continue; }
        else       { if (!diag) continue; kb = qb; isdiag = true; }
        nproc++;
        const uint4* gk = (const uint4*)(krb + (((size_t)bh*S_ + (kb<<6)) << 6));
        const uint4* gv = (const uint4*)(vrb + (((size_t)bh*S_ + (kb<<6)) << 6));
        __syncthreads();
        uint4* sk = (uint4*)Ks; uint4* sv = (uint4*)Vs;
        sk[tid] = gk[tid]; sk[tid+256] = gk[tid+256];
        sv[tid] = gv[tid]; sv[tid+256] = gv[tid+256];
        __syncthreads();
        #pragma unroll 1
        for (int i0 = 0; i0 < 64; i0 += 8) {
            float s8[8];
            #pragma unroll
            for (int u=0;u<8;u++) {
                const int i = i0+u;
                unsigned int kw[8];
                *(uint4*)&kw[0] = *(const uint4*)&Ks[(i<<6)+(dc<<4)];
                *(uint4*)&kw[4] = *(const uint4*)&Ks[(i<<6)+(dc<<4)+8];
                float acc = 0.f;
                #pragma unroll
                for (int p2=0;p2<8;p2++) {
                    acc = fmaf(q[2*p2],   __uint_as_float(kw[p2]<<16),        acc);
                    acc = fmaf(q[2*p2+1], __uint_as_float(kw[p2]&0xffff0000u), acc);
                }
                acc += __shfl_xor(acc, 16);
                acc += __shfl_xor(acc, 32);
                s8[u] = (isdiag && i > ql) ? -1e30f : acc*0.125f;
            }
            float bmax = s8[0];
            #pragma unroll
            for (int u=1;u<8;u++) bmax = fmaxf(bmax, s8[u]);
            const float mnew = fmaxf(mrun, bmax);
            const float cf = __expf(mrun - mnew);   // exp(-inf)=0 on first chunk
            lrun *= cf;
            #pragma unroll
            for (int d=0;d<16;d++) o[d] *= cf;
            #pragma unroll
            for (int u=0;u<8;u++) {
                const float pw = __expf(s8[u]-mnew);  // masked: exp(-1e30-m)=0
                lrun += pw;
                unsigned int vw[8];
                *(uint4*)&vw[0] = *(const uint4*)&Vs[((i0+u)<<6)+(dc<<4)];
                *(uint4*)&vw[4] = *(const uint4*)&Vs[((i0+u)<<6)+(dc<<4)+8];
                #pragma unroll
                for (int p2=0;p2<8;p2++) {
                    o[2*p2]   = fmaf(pw, __uint_as_float(vw[p2]<<16),        o[2*p2]);
                    o[2*p2+1] = fmaf(pw, __uint_as_float(vw[p2]&0xffff0000u), o[2*p2+1]);
                }
            }
            mrun = mnew;
        }
    }

    unsigned short* op = attno + (((size_t)(b*S_ + qpos)) << 10) + (h << 6) + (dc << 4);
    float res[16];
    if (nproc == 0) {
        const float* vm = vmeanp + (bh << 6) + (dc << 4);
        #pragma unroll
        for (int d=0;d<16;d++) res[d] = vm[d];
    } else {
        const float inv = 1.0f / lrun;
        #pragma unroll
        for (int d=0;d<16;d++) res[d] = o[d]*inv;
    }
    uint4 w0, w1;
    w0.x = pack2(res[0],  res[1]);  w0.y = pack2(res[2],  res[3]);
    w0.z = pack2(res[4],  res[5]);  w0.w = pack2(res[6],  res[7]);
    w1.x = pack2(res[8],  res[9]);  w1.y = pack2(res[10], res[11]);
    w1.z = pack2(res[12], res[13]); w1.w = pack2(res[14], res[15]);
    *(uint4*)op = w0;
    *(uint4*)(op+8) = w1;
}

extern "C" void kernel_launch(void* const* d_in, const int* in_sizes, int n_in,
                              void* d_out, int out_size, void* d_ws, size_t ws_size,
                              hipStream_t stream) {
    (void)in_sizes; (void)n_in; (void)out_size; (void)ws_size;
    const float* x     = (const float*)d_in[0];
    const float* w_q   = (const float*)d_in[1];
    const float* w_kvd = (const float*)d_in[2];
    const float* w_kvu = (const float*)d_in[3];
    const float* w_o   = (const float*)d_in[4];
    const float* w_sc  = (const float*)d_in[5];
    float* out = (float*)d_out;

    char* p = (char*)d_ws;
    auto alloc = [&](size_t bytes) -> void* {
        void* r = (void*)p;
        p += (bytes + 255) & ~(size_t)255;
        return r;
    };
    float* cosT  = (float*)alloc((size_t)S_*HD_*4);
    float* sinT  = (float*)alloc((size_t)S_*HD_*4);
    float* qlin  = (float*)alloc((size_t)BS_*D_*4);     // reused as attnob (bf16)
    float* kv    = (float*)alloc((size_t)BS_*2*D_*4);
    float* qr    = (float*)alloc((size_t)BS_*D_*4);
    unsigned short* xb    = (unsigned short*)alloc((size_t)BS_*D_*2);
    unsigned short* wqb   = (unsigned short*)alloc((size_t)D_*D_*2);
    unsigned short* wkdb  = (unsigned short*)alloc((size_t)R_*D_*2);
    unsigned short* wkub  = (unsigned short*)alloc((size_t)2*D_*R_*2);
    unsigned short* wob   = (unsigned short*)alloc((size_t)D_*D_*2);
    unsigned short* latb  = (unsigned short*)alloc((size_t)BS_*R_*2);
    unsigned short* krb   = (unsigned short*)alloc((size_t)BS_*D_*2);
    unsigned short* vrb   = (unsigned short*)alloc((size_t)BS_*D_*2);
    float* scores = (float*)alloc((size_t)B_*NBLK*4);
    int*   sel    = (int*)  alloc((size_t)B_*TOPK_*4);
    float* vmeanp = (float*)alloc((size_t)B_*H_*HD_*4);
    unsigned short* attnob = (unsigned short*)qlin;     // qlin dead after reorg2

    rope_tables_k<<<(S_*HD_+255)/256, 256, 0, stream>>>(cosT, sinT);
    cvt_bf16_k<<<(BS_*D_)/2048,   256, 0, stream>>>(x,     xb,   BS_*D_);
    cvt_bf16_k<<<(D_*D_)/2048,    256, 0, stream>>>(w_q,   wqb,  D_*D_);
    cvt_bf16_k<<<(R_*D_)/2048,    256, 0, stream>>>(w_kvd, wkdb, R_*D_);
    cvt_bf16_k<<<(2*D_*R_)/2048,  256, 0, stream>>>(w_kvu, wkub, 2*D_*R_);
    cvt_bf16_k<<<(D_*D_)/2048,    256, 0, stream>>>(w_o,   wob,  D_*D_);

    gemm_mfma_k<false><<<dim3(D_/128,   BS_/128), 256, 0, stream>>>(xb,   wqb,  qlin, BS_, D_,   D_);
    gemm_mfma_k<true ><<<dim3(R_/128,   BS_/128), 256, 0, stream>>>(xb,   wkdb, latb, BS_, R_,   D_);
    gemm_mfma_k<false><<<dim3(2*D_/128, BS_/128), 256, 0, stream>>>(latb, wkub, kv,   BS_, 2*D_, R_);

    block_scores_k<<<B_*NBLK, 256, 0, stream>>>(x, w_sc, scores);
    topk_sel_k<<<1, 64, 0, stream>>>(scores, sel);
    reorg2_k<<<(B_*H_*S_*HD_)/256, 256, 0, stream>>>(qlin, kv, cosT, sinT, qr, krb, vrb);
    vmean_k<<<B_*H_, 256, 0, stream>>>(vrb, vmeanp);
    attn_k<<<B_*H_*NBLK, 256, 0, stream>>>(qr, krb, vrb, sel, vmeanp, attnob);
    gemm_mfma_k<false><<<dim3(D_/128, BS_/128), 256, 0, stream>>>(attnob, wob, out, BS_, D_, D_);
}

// Round 4
// 271.679 us; speedup vs baseline: 3.4442x; 1.5108x over previous
//
#include <hip/hip_runtime.h>
#include <hip/hip_bf16.h>
#include <math.h>

#define B_ 2
#define S_ 2048
#define D_ 1024
#define H_ 16
#define HD_ 64
#define R_ 128
#define NBLK 32
#define TOPK_ 4
#define BS_ (B_*S_)

typedef __attribute__((ext_vector_type(8))) short bf16x8;
typedef __attribute__((ext_vector_type(4))) float f32x4;

__device__ __forceinline__ unsigned short f2bf(float f) {
    unsigned int u = __float_as_uint(f);
    u += 0x7fffu + ((u >> 16) & 1u);
    return (unsigned short)(u >> 16);
}
__device__ __forceinline__ float bf2f(unsigned short h) {
    return __uint_as_float(((unsigned int)h) << 16);
}
__device__ __forceinline__ unsigned int pack2(float a, float b) {
    return (unsigned int)f2bf(a) | ((unsigned int)f2bf(b) << 16);
}
__device__ __forceinline__ void gload_lds16(const void* g, void* l) {
    __builtin_amdgcn_global_load_lds((const __attribute__((address_space(1))) void*)g,
                                     (__attribute__((address_space(3))) void*)l, 16, 0, 0);
}

// ---------------- fp32 -> bf16 convert (8 elems/thread) ----------------
__global__ __launch_bounds__(256) void cvt_bf16_k(const float* __restrict__ in,
        unsigned short* __restrict__ out, int n) {
    int i = (blockIdx.x*256 + threadIdx.x)*8;
    if (i >= n) return;
    float4 a = *(const float4*)&in[i];
    float4 b = *(const float4*)&in[i+4];
    uint4 o;
    o.x = pack2(a.x, a.y);
    o.y = pack2(a.z, a.w);
    o.z = pack2(b.x, b.y);
    o.w = pack2(b.z, b.w);
    *(uint4*)&out[i] = o;
}

// ---------------- RoPE tables ----------------
__global__ void rope_tables_k(float* __restrict__ cosT, float* __restrict__ sinT) {
    int idx = blockIdx.x*256 + threadIdx.x;
    if (idx >= S_*HD_) return;
    int s  = idx >> 6;
    int hd = idx & 63;
    int j = (hd < 32) ? hd : hd - 32;
    float inv = powf(100000.0f, -((float)(2*j) / 64.0f));
    float fr = (float)s * inv;
    cosT[idx] = cosf(fr);
    sinT[idx] = sinf(fr);
}

// ---------------- MFMA GEMM: C[M,N] = A[M,K] @ B[N,K]^T, 128x64 tile, BK=64 ----------------
template<bool OUT_BF16>
__global__ __launch_bounds__(256) void gemm_mfma_k(const unsigned short* __restrict__ A,
        const unsigned short* __restrict__ Bm, void* __restrict__ Cv,
        int M, int N, int K) {
    __shared__ unsigned short As[128*64];
    __shared__ unsigned short Bs[64*64];
    const int tid  = threadIdx.x;
    const int wave = tid >> 6, lane = tid & 63;
    const int bm = blockIdx.y << 7, bn = blockIdx.x << 6;
    const int g  = lane >> 4, qc = lane & 15;
    const int srow  = lane >> 3;             // row within 8-row chunk
    const int sslot = (lane & 7) ^ srow;     // inverse-swizzled global 16B slot

    f32x4 acc[2][4];
    #pragma unroll
    for (int m=0;m<2;m++)
        #pragma unroll
        for (int n=0;n<4;n++)
            acc[m][n] = (f32x4){0.f,0.f,0.f,0.f};

    for (int k0 = 0; k0 < K; k0 += 64) {
        __syncthreads();
        #pragma unroll
        for (int it = 0; it < 4; ++it) {
            const int chunk = (it << 2) | wave;       // 0..15
            const int row   = (chunk << 3) | srow;    // 0..127
            gload_lds16(A + (size_t)(bm + row) * K + k0 + (sslot << 3), &As[chunk << 9]);
        }
        #pragma unroll
        for (int it = 0; it < 2; ++it) {
            const int chunk = (it << 2) | wave;       // 0..7
            const int row   = (chunk << 3) | srow;    // 0..63
            gload_lds16(Bm + (size_t)(bn + row) * K + k0 + (sslot << 3), &Bs[chunk << 9]);
        }
        __syncthreads();
        #pragma unroll
        for (int ks = 0; ks < 2; ++ks) {
            const int swb = ((ks << 2) | g) ^ (lane & 7);  // swizzled read slot
            bf16x8 af[2], bfr[4];
            #pragma unroll
            for (int m = 0; m < 2; ++m)
                af[m]  = *(const bf16x8*)&As[(((wave << 5) + (m << 4) + qc) << 6) + (swb << 3)];
            #pragma unroll
            for (int n = 0; n < 4; ++n)
                bfr[n] = *(const bf16x8*)&Bs[(((n << 4) + qc) << 6) + (swb << 3)];
            #pragma unroll
            for (int m = 0; m < 2; ++m)
                #pragma unroll
                for (int n = 0; n < 4; ++n)
                    acc[m][n] = __builtin_amdgcn_mfma_f32_16x16x32_bf16(af[m], bfr[n], acc[m][n], 0, 0, 0);
        }
    }
    #pragma unroll
    for (int m = 0; m < 2; ++m) {
        const int r0 = bm + (wave << 5) + (m << 4) + (g << 2);
        #pragma unroll
        for (int n = 0; n < 4; ++n) {
            const int c = bn + (n << 4) + qc;
            #pragma unroll
            for (int j = 0; j < 4; ++j) {
                if (OUT_BF16) ((unsigned short*)Cv)[(size_t)(r0 + j) * N + c] = f2bf(acc[m][n][j]);
                else          ((float*)Cv)[(size_t)(r0 + j) * N + c] = acc[m][n][j];
            }
        }
    }
}

// ---------------- block scores ----------------
__global__ __launch_bounds__(256) void block_scores_k(const float* __restrict__ x,
        const float* __restrict__ wsc, float* __restrict__ scores) {
    int b  = blockIdx.x / NBLK;
    int kb = blockIdx.x % NBLK;
    const float* xb = x + ((size_t)b*S_ + (size_t)kb*64)*D_;
    float p = 0.0f;
    for (int i = threadIdx.x; i < 64*D_; i += 256)
        p += xb[i] * wsc[i & (D_-1)];
    __shared__ float red[256];
    red[threadIdx.x] = p;
    __syncthreads();
    for (int off=128; off>0; off>>=1) {
        if (threadIdx.x < off) red[threadIdx.x] += red[threadIdx.x+off];
        __syncthreads();
    }
    if (threadIdx.x == 0) scores[b*NBLK+kb] = red[0] * (1.0f/64.0f);
}

// ---------------- top-4 (strict > == lowest index on ties) ----------------
__global__ void topk_sel_k(const float* __restrict__ scores, int* __restrict__ sel) {
    int b = threadIdx.x;
    if (b >= B_) return;
    float sc[NBLK];
    for (int i=0;i<NBLK;i++) sc[i] = scores[b*NBLK+i];
    int ch[TOPK_];
    for (int j=0;j<TOPK_;j++) {
        float best = -INFINITY; int bi = 0;
        for (int i=0;i<NBLK;i++)
            if (sc[i] > best) { best = sc[i]; bi = i; }
        ch[j] = bi;
        sc[bi] = -INFINITY;
    }
    for (int a=0;a<TOPK_;a++)
        for (int c=a+1;c<TOPK_;c++)
            if (ch[c] < ch[a]) { int t=ch[a]; ch[a]=ch[c]; ch[c]=t; }
    for (int j=0;j<TOPK_;j++) sel[b*TOPK_+j] = ch[j];
}

// ---------------- RoPE + reorg: qrb/krb/vrb bf16 in [B,H,S,HD] ----------------
__global__ __launch_bounds__(256) void reorg2_k(const float* __restrict__ qlin,
        const float* __restrict__ kv, const float* __restrict__ cosT,
        const float* __restrict__ sinT, unsigned short* __restrict__ qrb,
        unsigned short* __restrict__ krb, unsigned short* __restrict__ vrb) {
    int idx = blockIdx.x*256 + threadIdx.x;   // [B,H,S,HD] linear
    int hd = idx & 63;
    int s  = (idx >> 6) & (S_-1);
    int h  = (idx >> 17) & (H_-1);
    int b  = idx >> 21;
    float c  = cosT[(s<<6)+hd];
    float sn = sinT[(s<<6)+hd];
    size_t rowq = (size_t)(b*S_+s)*D_ + h*HD_;
    float qv = qlin[rowq + hd];
    float qrot = (hd < 32) ? -qlin[rowq + hd + 32] : qlin[rowq + hd - 32];
    qrb[idx] = f2bf(qv*c + qrot*sn);
    size_t rowk = (size_t)(b*S_+s)*(2*D_) + h*HD_;
    float kvv = kv[rowk + hd];
    float krot = (hd < 32) ? -kv[rowk + hd + 32] : kv[rowk + hd - 32];
    krb[idx] = f2bf(kvv*c + krot*sn);
    vrb[idx] = f2bf(kv[rowk + D_ + hd]);
}

// ---------------- V transpose per 64-block: vtb[bh,kb][d][k] ----------------
__global__ __launch_bounds__(256) void vt_k(const unsigned short* __restrict__ vrb,
        unsigned short* __restrict__ vtb) {
    const int wg = blockIdx.x;    // bh*NBLK + kb
    __shared__ unsigned short T[64][72];
    const uint4* src = (const uint4*)(vrb + (size_t)wg*4096);
    #pragma unroll
    for (int u=0;u<2;u++) {
        int idx = (u<<8) + threadIdx.x;   // 0..511
        int r = idx>>3, c = (idx&7)<<3;
        *(uint4*)&T[r][c] = src[idx];
    }
    __syncthreads();
    unsigned short* dst = vtb + (size_t)wg*4096;
    #pragma unroll
    for (int u=0;u<2;u++) {
        int idx = (u<<8) + threadIdx.x;
        int dd = idx>>3, k0 = (idx&7)<<3;
        unsigned short tmp[8];
        #pragma unroll
        for (int j=0;j<8;j++) tmp[j] = T[k0+j][dd];
        *(uint4*)&dst[(size_t)idx<<3] = *(uint4*)tmp;   // dst[dd*64 + k0]
    }
}

// ---------------- vmean (for rows with zero allowed keys) ----------------
__global__ __launch_bounds__(256) void vmean_k(const unsigned short* __restrict__ vrb,
        float* __restrict__ vm) {
    int bh = blockIdx.x;
    int hd = threadIdx.x & 63;
    int sc = threadIdx.x >> 6;
    const unsigned short* vp = vrb + (((size_t)bh*S_ + sc*512) << 6) + hd;
    float s = 0.0f;
    for (int i=0;i<512;i++) s += bf2f(vp[(size_t)i*64]);
    __shared__ float red[256];
    red[threadIdx.x] = s;
    __syncthreads();
    if (threadIdx.x < 64)
        vm[bh*64+hd] = (red[hd]+red[hd+64]+red[hd+128]+red[hd+192]) * (1.0f/(float)S_);
}

// ---------------- MFMA block-sparse attention: wg=(b,h,qb), 4 waves x 16 q-rows ----------------
__global__ __launch_bounds__(256) void attn_mfma_k(const unsigned short* __restrict__ qrb,
        const unsigned short* __restrict__ krb, const unsigned short* __restrict__ vtb,
        const int* __restrict__ sel, const float* __restrict__ vmeanp,
        unsigned short* __restrict__ attno) {
    const int qb = blockIdx.x & (NBLK-1);
    const int bh = blockIdx.x >> 5;
    const int b  = bh >> 4;
    const int h  = bh & 15;
    const int tid  = threadIdx.x;
    const int wave = tid >> 6, lane = tid & 63;
    const int g = lane >> 4, qc = lane & 15;

    __shared__ unsigned short Ks[64][72];      // [key][d]
    __shared__ unsigned short Vt[64][72];      // [d][key]
    __shared__ unsigned short Pl[4][16][72];   // per-wave P [q][key]
    __shared__ float cfl[4][16];
    __shared__ float lvl[4][16];

    int selb[4];
    #pragma unroll
    for (int j=0;j<4;j++) selb[j] = sel[(b<<2)+j];
    const bool diag = (selb[0]==qb)|(selb[1]==qb)|(selb[2]==qb)|(selb[3]==qb);

    // Q B-frags (per wave: rows qb*64 + wave*16 .. +16)
    const unsigned short* qp = qrb + (((size_t)bh*S_ + (qb<<6) + (wave<<4) + qc) << 6);
    bf16x8 bq[2];
    bq[0] = *(const bf16x8*)(qp + (g<<3));
    bq[1] = *(const bf16x8*)(qp + 32 + (g<<3));

    f32x4 oacc[4];
    #pragma unroll
    for (int n=0;n<4;n++) oacc[n] = (f32x4){0.f,0.f,0.f,0.f};
    float mrun = -INFINITY, lrun = 0.f;
    int nproc = 0;
    const int qib = (wave<<4) + qc;   // this lane's q-row within the 64-block

    for (int j = 0; j < 5; ++j) {     // wg-uniform control flow
        int kb; bool isdiag;
        if (j < 4) { kb = selb[j]; isdiag = false; if (kb >= qb) continue; }
        else       { if (!diag) continue; kb = qb; isdiag = true; }
        nproc++;
        const uint4* gk = (const uint4*)(krb + (((size_t)bh*S_ + (kb<<6)) << 6));
        const uint4* gv = (const uint4*)(vtb + (((size_t)(bh*NBLK + kb)) << 12));
        __syncthreads();
        #pragma unroll
        for (int u=0;u<2;u++) {
            int idx = (u<<8) + tid;      // 0..511
            int r = idx>>3, c = (idx&7)<<3;
            *(uint4*)&Ks[r][c] = gk[idx];
            *(uint4*)&Vt[r][c] = gv[idx];
        }
        __syncthreads();

        // S^T = K @ Q^T : lane holds q-col=qc, keys 16m+4g+{0..3}
        f32x4 sf[4];
        #pragma unroll
        for (int m=0;m<4;m++) sf[m] = (f32x4){0.f,0.f,0.f,0.f};
        #pragma unroll
        for (int ks=0;ks<2;ks++)
            #pragma unroll
            for (int m=0;m<4;m++) {
                bf16x8 ak = *(const bf16x8*)&Ks[(m<<4)+qc][(ks<<5)+(g<<3)];
                sf[m] = __builtin_amdgcn_mfma_f32_16x16x32_bf16(ak, bq[ks], sf[m], 0, 0, 0);
            }

        float s[16];
        float bmax = -INFINITY;
        #pragma unroll
        for (int m=0;m<4;m++)
            #pragma unroll
            for (int r2=0;r2<4;r2++) {
                const int kl = (m<<4)+(g<<2)+r2;
                float v = sf[m][r2]*0.125f;
                if (isdiag && kl > qib) v = -1e30f;
                s[(m<<2)+r2] = v;
                bmax = fmaxf(bmax, v);
            }
        bmax = fmaxf(bmax, __shfl_xor(bmax, 16));
        bmax = fmaxf(bmax, __shfl_xor(bmax, 32));
        const float mnew = fmaxf(mrun, bmax);
        const float cf = __expf(mrun - mnew);
        float ls = 0.f;
        #pragma unroll
        for (int m=0;m<4;m++) {
            float p0 = __expf(s[(m<<2)+0]-mnew);
            float p1 = __expf(s[(m<<2)+1]-mnew);
            float p2 = __expf(s[(m<<2)+2]-mnew);
            float p3 = __expf(s[(m<<2)+3]-mnew);
            ls += p0+p1+p2+p3;
            const int koff = (m<<4)+(g<<2);
            *(unsigned int*)&Pl[wave][qc][koff]   = pack2(p0,p1);
            *(unsigned int*)&Pl[wave][qc][koff+2] = pack2(p2,p3);
        }
        ls += __shfl_xor(ls, 16);
        ls += __shfl_xor(ls, 32);
        lrun = lrun*cf + ls;
        cfl[wave][qc] = cf;
        // rescale O rows (lane's O-rows are 4g+r, need cf of those rows)
        f32x4 cf4 = *(const f32x4*)&cfl[wave][g<<2];
        #pragma unroll
        for (int n=0;n<4;n++) oacc[n] *= cf4;
        // O += P @ V  (A = P from LDS, B = V^T rows from LDS)
        #pragma unroll
        for (int ks=0;ks<2;ks++) {
            bf16x8 pa = *(const bf16x8*)&Pl[wave][qc][(ks<<5)+(g<<3)];
            #pragma unroll
            for (int n=0;n<4;n++) {
                bf16x8 vb = *(const bf16x8*)&Vt[(n<<4)+qc][(ks<<5)+(g<<3)];
                oacc[n] = __builtin_amdgcn_mfma_f32_16x16x32_bf16(pa, vb, oacc[n], 0, 0, 0);
            }
        }
        mrun = mnew;
    }

    f32x4 il4 = (f32x4){0.f,0.f,0.f,0.f};
    if (nproc) {
        lvl[wave][qc] = 1.0f / lrun;
        il4 = *(const f32x4*)&lvl[wave][g<<2];
    }
    #pragma unroll
    for (int n=0;n<4;n++)
        #pragma unroll
        for (int r2=0;r2<4;r2++) {
            float val = nproc ? oacc[n][r2]*il4[r2]
                              : vmeanp[(bh<<6)+(n<<4)+qc];
            const int row = (qb<<6) + (wave<<4) + (g<<2) + r2;
            attno[(((size_t)(b*S_+row))<<10) + (h<<6) + (n<<4) + qc] = f2bf(val);
        }
}

extern "C" void kernel_launch(void* const* d_in, const int* in_sizes, int n_in,
                              void* d_out, int out_size, void* d_ws, size_t ws_size,
                              hipStream_t stream) {
    (void)in_sizes; (void)n_in; (void)out_size; (void)ws_size;
    const float* x     = (const float*)d_in[0];
    const float* w_q   = (const float*)d_in[1];
    const float* w_kvd = (const float*)d_in[2];
    const float* w_kvu = (const float*)d_in[3];
    const float* w_o   = (const float*)d_in[4];
    const float* w_sc  = (const float*)d_in[5];
    float* out = (float*)d_out;

    char* p = (char*)d_ws;
    auto alloc = [&](size_t bytes) -> void* {
        void* r = (void*)p;
        p += (bytes + 255) & ~(size_t)255;
        return r;
    };
    float* cosT  = (float*)alloc((size_t)S_*HD_*4);
    float* sinT  = (float*)alloc((size_t)S_*HD_*4);
    float* qlin  = (float*)alloc((size_t)BS_*D_*4);     // reused as attnob (bf16)
    float* kv    = (float*)alloc((size_t)BS_*2*D_*4);
    unsigned short* xb    = (unsigned short*)alloc((size_t)BS_*D_*2);
    unsigned short* wqb   = (unsigned short*)alloc((size_t)D_*D_*2);
    unsigned short* wkdb  = (unsigned short*)alloc((size_t)R_*D_*2);
    unsigned short* wkub  = (unsigned short*)alloc((size_t)2*D_*R_*2);
    unsigned short* wob   = (unsigned short*)alloc((size_t)D_*D_*2);
    unsigned short* latb  = (unsigned short*)alloc((size_t)BS_*R_*2);
    unsigned short* qrb   = (unsigned short*)alloc((size_t)BS_*D_*2);
    unsigned short* krb   = (unsigned short*)alloc((size_t)BS_*D_*2);
    unsigned short* vrb   = (unsigned short*)alloc((size_t)BS_*D_*2);
    unsigned short* vtb   = (unsigned short*)alloc((size_t)BS_*D_*2);
    float* scores = (float*)alloc((size_t)B_*NBLK*4);
    int*   sel    = (int*)  alloc((size_t)B_*TOPK_*4);
    float* vmeanp = (float*)alloc((size_t)B_*H_*HD_*4);
    unsigned short* attnob = (unsigned short*)qlin;     // qlin dead after reorg2

    rope_tables_k<<<(S_*HD_+255)/256, 256, 0, stream>>>(cosT, sinT);
    cvt_bf16_k<<<(BS_*D_)/2048,   256, 0, stream>>>(x,     xb,   BS_*D_);
    cvt_bf16_k<<<(D_*D_)/2048,    256, 0, stream>>>(w_q,   wqb,  D_*D_);
    cvt_bf16_k<<<(R_*D_)/2048,    256, 0, stream>>>(w_kvd, wkdb, R_*D_);
    cvt_bf16_k<<<(2*D_*R_)/2048,  256, 0, stream>>>(w_kvu, wkub, 2*D_*R_);
    cvt_bf16_k<<<(D_*D_)/2048,    256, 0, stream>>>(w_o,   wob,  D_*D_);

    gemm_mfma_k<false><<<dim3(D_/64,   BS_/128), 256, 0, stream>>>(xb,   wqb,  qlin, BS_, D_,   D_);
    gemm_mfma_k<true ><<<dim3(R_/64,   BS_/128), 256, 0, stream>>>(xb,   wkdb, latb, BS_, R_,   D_);
    gemm_mfma_k<false><<<dim3(2*D_/64, BS_/128), 256, 0, stream>>>(latb, wkub, kv,   BS_, 2*D_, R_);

    block_scores_k<<<B_*NBLK, 256, 0, stream>>>(x, w_sc, scores);
    topk_sel_k<<<1, 64, 0, stream>>>(scores, sel);
    reorg2_k<<<(B_*H_*S_*HD_)/256, 256, 0, stream>>>(qlin, kv, cosT, sinT, qrb, krb, vrb);
    vt_k<<<B_*H_*NBLK, 256, 0, stream>>>(vrb, vtb);
    vmean_k<<<B_*H_, 256, 0, stream>>>(vrb, vmeanp);
    attn_mfma_k<<<B_*H_*NBLK, 256, 0, stream>>>(qrb, krb, vtb, sel, vmeanp, attnob);
    gemm_mfma_k<false><<<dim3(D_/64, BS_/128), 256, 0, stream>>>(attnob, wob, out, BS_, D_, D_);
}

// Round 5
// 202.517 us; speedup vs baseline: 4.6204x; 1.3415x over previous
//
#include <hip/hip_runtime.h>
#include <hip/hip_bf16.h>
#include <math.h>

#define B_ 2
#define S_ 2048
#define D_ 1024
#define H_ 16
#define HD_ 64
#define R_ 128
#define NBLK 32
#define TOPK_ 4
#define BS_ (B_*S_)

typedef __attribute__((ext_vector_type(8))) short bf16x8;
typedef __attribute__((ext_vector_type(4))) float f32x4;

__device__ __forceinline__ unsigned short f2bf(float f) {
    unsigned int u = __float_as_uint(f);
    u += 0x7fffu + ((u >> 16) & 1u);
    return (unsigned short)(u >> 16);
}
__device__ __forceinline__ float bf2f(unsigned short h) {
    return __uint_as_float(((unsigned int)h) << 16);
}
__device__ __forceinline__ unsigned int pack2(float a, float b) {
    return (unsigned int)f2bf(a) | ((unsigned int)f2bf(b) << 16);
}
__device__ __forceinline__ void gload_lds16(const void* g, void* l) {
    __builtin_amdgcn_global_load_lds((const __attribute__((address_space(1))) void*)g,
                                     (__attribute__((address_space(3))) void*)l, 16, 0, 0);
}

// ---------------- fp32 -> bf16 convert (8 elems/thread) ----------------
__global__ __launch_bounds__(256) void cvt_bf16_k(const float* __restrict__ in,
        unsigned short* __restrict__ out, int n) {
    int i = (blockIdx.x*256 + threadIdx.x)*8;
    if (i >= n) return;
    float4 a = *(const float4*)&in[i];
    float4 b = *(const float4*)&in[i+4];
    uint4 o;
    o.x = pack2(a.x, a.y);
    o.y = pack2(a.z, a.w);
    o.z = pack2(b.x, b.y);
    o.w = pack2(b.z, b.w);
    *(uint4*)&out[i] = o;
}

// ---------------- RoPE tables ----------------
__global__ void rope_tables_k(float* __restrict__ cosT, float* __restrict__ sinT) {
    int idx = blockIdx.x*256 + threadIdx.x;
    if (idx >= S_*HD_) return;
    int s  = idx >> 6;
    int hd = idx & 63;
    int j = (hd < 32) ? hd : hd - 32;
    float inv = powf(100000.0f, -((float)(2*j) / 64.0f));
    float fr = (float)s * inv;
    cosT[idx] = cosf(fr);
    sinT[idx] = sinf(fr);
}

// ---------------- MFMA GEMM: C[M,N] = A[M,K] @ B[N,K]^T, 128x64 tile, BK=64 ----------------
template<bool OUT_BF16>
__global__ __launch_bounds__(256) void gemm_mfma_k(const unsigned short* __restrict__ A,
        const unsigned short* __restrict__ Bm, void* __restrict__ Cv,
        int M, int N, int K) {
    __shared__ unsigned short As[128*64];
    __shared__ unsigned short Bs[64*64];
    const int tid  = threadIdx.x;
    const int wave = tid >> 6, lane = tid & 63;
    const int bm = blockIdx.y << 7, bn = blockIdx.x << 6;
    const int g  = lane >> 4, qc = lane & 15;
    const int srow  = lane >> 3;             // row within 8-row chunk
    const int sslot = (lane & 7) ^ srow;     // inverse-swizzled global 16B slot

    f32x4 acc[2][4];
    #pragma unroll
    for (int m=0;m<2;m++)
        #pragma unroll
        for (int n=0;n<4;n++)
            acc[m][n] = (f32x4){0.f,0.f,0.f,0.f};

    for (int k0 = 0; k0 < K; k0 += 64) {
        __syncthreads();
        #pragma unroll
        for (int it = 0; it < 4; ++it) {
            const int chunk = (it << 2) | wave;       // 0..15
            const int row   = (chunk << 3) | srow;    // 0..127
            gload_lds16(A + (size_t)(bm + row) * K + k0 + (sslot << 3), &As[chunk << 9]);
        }
        #pragma unroll
        for (int it = 0; it < 2; ++it) {
            const int chunk = (it << 2) | wave;       // 0..7
            const int row   = (chunk << 3) | srow;    // 0..63
            gload_lds16(Bm + (size_t)(bn + row) * K + k0 + (sslot << 3), &Bs[chunk << 9]);
        }
        __syncthreads();
        #pragma unroll
        for (int ks = 0; ks < 2; ++ks) {
            const int swb = ((ks << 2) | g) ^ (lane & 7);  // swizzled read slot
            bf16x8 af[2], bfr[4];
            #pragma unroll
            for (int m = 0; m < 2; ++m)
                af[m]  = *(const bf16x8*)&As[(((wave << 5) + (m << 4) + qc) << 6) + (swb << 3)];
            #pragma unroll
            for (int n = 0; n < 4; ++n)
                bfr[n] = *(const bf16x8*)&Bs[(((n << 4) + qc) << 6) + (swb << 3)];
            #pragma unroll
            for (int m = 0; m < 2; ++m)
                #pragma unroll
                for (int n = 0; n < 4; ++n)
                    acc[m][n] = __builtin_amdgcn_mfma_f32_16x16x32_bf16(af[m], bfr[n], acc[m][n], 0, 0, 0);
        }
    }
    #pragma unroll
    for (int m = 0; m < 2; ++m) {
        const int r0 = bm + (wave << 5) + (m << 4) + (g << 2);
        #pragma unroll
        for (int n = 0; n < 4; ++n) {
            const int c = bn + (n << 4) + qc;
            #pragma unroll
            for (int j = 0; j < 4; ++j) {
                if (OUT_BF16) ((unsigned short*)Cv)[(size_t)(r0 + j) * N + c] = f2bf(acc[m][n][j]);
                else          ((float*)Cv)[(size_t)(r0 + j) * N + c] = acc[m][n][j];
            }
        }
    }
}

// ---------------- row scores: one wave per x-row, coalesced ----------------
__global__ __launch_bounds__(256) void rowscore_k(const float* __restrict__ x,
        const float* __restrict__ wsc, float* __restrict__ rows) {
    const int wid  = (blockIdx.x << 2) + (threadIdx.x >> 6);  // 0..1023
    const int lane = threadIdx.x & 63;
    #pragma unroll
    for (int r = 0; r < 4; ++r) {
        const int row = (wid << 2) + r;                        // 0..4095
        const float* xp = x + (size_t)row * D_;
        float acc = 0.f;
        #pragma unroll
        for (int j = 0; j < 4; ++j) {
            const int off = ((j << 6) + lane) << 2;            // coalesced float4
            float4 xv = *(const float4*)&xp[off];
            float4 wv = *(const float4*)&wsc[off];
            acc = fmaf(xv.x, wv.x, acc);
            acc = fmaf(xv.y, wv.y, acc);
            acc = fmaf(xv.z, wv.z, acc);
            acc = fmaf(xv.w, wv.w, acc);
        }
        #pragma unroll
        for (int m = 1; m <= 32; m <<= 1) acc += __shfl_xor(acc, m);
        if (lane == 0) rows[row] = acc;
    }
}

// ---------------- block sums + top-4 (strict > == lowest index on ties) ----------------
__global__ __launch_bounds__(256) void blocktopk_k(const float* __restrict__ rows,
        int* __restrict__ sel) {
    __shared__ float bs[64];
    const int bk = threadIdx.x >> 2, qt = threadIdx.x & 3;     // block 0..63, quarter
    const float* rp = rows + (bk << 6) + (qt << 4);
    float p = 0.f;
    #pragma unroll
    for (int i = 0; i < 16; ++i) p += rp[i];
    p += __shfl_xor(p, 1);
    p += __shfl_xor(p, 2);
    if (qt == 0) bs[bk] = p;
    __syncthreads();
    if (threadIdx.x < B_) {
        const int b = threadIdx.x;
        float sc[NBLK];
        for (int i = 0; i < NBLK; ++i) sc[i] = bs[b * NBLK + i];
        for (int j = 0; j < TOPK_; ++j) {
            float best = -INFINITY; int bi = 0;
            for (int i = 0; i < NBLK; ++i)
                if (sc[i] > best) { best = sc[i]; bi = i; }
            sel[b * TOPK_ + j] = bi;
            sc[bi] = -INFINITY;
        }
    }
}

// ---------------- RoPE + reorg: bf16 in, qrb/krb/vrb bf16 in [B,H,S,HD] ----------------
__global__ __launch_bounds__(256) void reorg2_k(const unsigned short* __restrict__ qlin,
        const unsigned short* __restrict__ kv, const float* __restrict__ cosT,
        const float* __restrict__ sinT, unsigned short* __restrict__ qrb,
        unsigned short* __restrict__ krb, unsigned short* __restrict__ vrb) {
    int idx = blockIdx.x*256 + threadIdx.x;   // [B,H,S,HD] linear
    int hd = idx & 63;
    int s  = (idx >> 6) & (S_-1);
    int h  = (idx >> 17) & (H_-1);
    int b  = idx >> 21;
    float c  = cosT[(s<<6)+hd];
    float sn = sinT[(s<<6)+hd];
    size_t rowq = (size_t)(b*S_+s)*D_ + h*HD_;
    float qv = bf2f(qlin[rowq + hd]);
    float qrot = (hd < 32) ? -bf2f(qlin[rowq + hd + 32]) : bf2f(qlin[rowq + hd - 32]);
    qrb[idx] = f2bf(qv*c + qrot*sn);
    size_t rowk = (size_t)(b*S_+s)*(2*D_) + h*HD_;
    float kvv = bf2f(kv[rowk + hd]);
    float krot = (hd < 32) ? -bf2f(kv[rowk + hd + 32]) : bf2f(kv[rowk + hd - 32]);
    krb[idx] = f2bf(kvv*c + krot*sn);
    vrb[idx] = kv[rowk + D_ + hd];
}

// ---------------- V transpose per 64-block: vtb[bh,kb][d][k] ----------------
__global__ __launch_bounds__(256) void vt_k(const unsigned short* __restrict__ vrb,
        unsigned short* __restrict__ vtb) {
    const int wg = blockIdx.x;    // bh*NBLK + kb
    __shared__ unsigned short T[64][72];
    const uint4* src = (const uint4*)(vrb + (size_t)wg*4096);
    #pragma unroll
    for (int u=0;u<2;u++) {
        int idx = (u<<8) + threadIdx.x;   // 0..511
        int r = idx>>3, c = (idx&7)<<3;
        *(uint4*)&T[r][c] = src[idx];
    }
    __syncthreads();
    unsigned short* dst = vtb + (size_t)wg*4096;
    #pragma unroll
    for (int u=0;u<2;u++) {
        int idx = (u<<8) + threadIdx.x;
        int dd = idx>>3, k0 = (idx&7)<<3;
        unsigned short tmp[8];
        #pragma unroll
        for (int j=0;j<8;j++) tmp[j] = T[k0+j][dd];
        *(uint4*)&dst[(size_t)idx<<3] = *(uint4*)tmp;   // dst[dd*64 + k0]
    }
}

// ---------------- vmean, coalesced: wave reads 8 rows/iter as lane-contiguous uint4 ----------------
__global__ __launch_bounds__(256) void vmean_k(const unsigned short* __restrict__ vrb,
        float* __restrict__ vm) {
    const int bh = blockIdx.x;
    const int wave = threadIdx.x >> 6, lane = threadIdx.x & 63;
    const int rsl = lane >> 3;     // row-sub 0..7
    const int csl = lane & 7;      // 16B col-slice 0..7
    float acc[8] = {0.f,0.f,0.f,0.f,0.f,0.f,0.f,0.f};
    const unsigned short* base = vrb + ((size_t)bh*S_ << 6);
    for (int it = 0; it < 64; ++it) {
        const int row = (wave << 9) + (it << 3) + rsl;
        uint4 v = *(const uint4*)(base + ((size_t)row << 6) + (csl << 3));
        const unsigned int w[4] = {v.x, v.y, v.z, v.w};
        #pragma unroll
        for (int j = 0; j < 4; ++j) {
            acc[2*j]   += __uint_as_float(w[j] << 16);
            acc[2*j+1] += __uint_as_float(w[j] & 0xffff0000u);
        }
    }
    #pragma unroll
    for (int m = 8; m <= 32; m <<= 1)
        #pragma unroll
        for (int j = 0; j < 8; ++j) acc[j] += __shfl_xor(acc[j], m);
    __shared__ float red[4][64];
    if (rsl == 0)
        #pragma unroll
        for (int j = 0; j < 8; ++j) red[wave][(csl << 3) + j] = acc[j];
    __syncthreads();
    const int t = threadIdx.x;
    if (t < 64)
        vm[(bh << 6) + t] = (red[0][t] + red[1][t] + red[2][t] + red[3][t]) * (1.0f / (float)S_);
}

// ---------------- MFMA block-sparse attention: wg=(b,h,qb), 4 waves x 16 q-rows ----------------
__global__ __launch_bounds__(256) void attn_mfma_k(const unsigned short* __restrict__ qrb,
        const unsigned short* __restrict__ krb, const unsigned short* __restrict__ vtb,
        const int* __restrict__ sel, const float* __restrict__ vmeanp,
        unsigned short* __restrict__ attno) {
    const int qb = blockIdx.x & (NBLK-1);
    const int bh = blockIdx.x >> 5;
    const int b  = bh >> 4;
    const int h  = bh & 15;
    const int tid  = threadIdx.x;
    const int wave = tid >> 6, lane = tid & 63;
    const int g = lane >> 4, qc = lane & 15;

    __shared__ unsigned short Ks[64][72];      // [key][d]
    __shared__ unsigned short Vt[64][72];      // [d][key]
    __shared__ unsigned short Pl[4][16][72];   // per-wave P [q][key]
    __shared__ float cfl[4][16];
    __shared__ float lvl[4][16];

    int selb[4];
    #pragma unroll
    for (int j=0;j<4;j++) selb[j] = sel[(b<<2)+j];
    const bool diag = (selb[0]==qb)|(selb[1]==qb)|(selb[2]==qb)|(selb[3]==qb);

    // Q B-frags (per wave: rows qb*64 + wave*16 .. +16)
    const unsigned short* qp = qrb + (((size_t)bh*S_ + (qb<<6) + (wave<<4) + qc) << 6);
    bf16x8 bq[2];
    bq[0] = *(const bf16x8*)(qp + (g<<3));
    bq[1] = *(const bf16x8*)(qp + 32 + (g<<3));

    f32x4 oacc[4];
    #pragma unroll
    for (int n=0;n<4;n++) oacc[n] = (f32x4){0.f,0.f,0.f,0.f};
    float mrun = -INFINITY, lrun = 0.f;
    int nproc = 0;
    const int qib = (wave<<4) + qc;   // this lane's q-row within the 64-block

    for (int j = 0; j < 5; ++j) {     // wg-uniform control flow
        int kb; bool isdiag;
        if (j < 4) { kb = selb[j]; isdiag = false; if (kb >= qb) continue; }
        else       { if (!diag) continue; kb = qb; isdiag = true; }
        nproc++;
        const uint4* gk = (const uint4*)(krb + (((size_t)bh*S_ + (kb<<6)) << 6));
        const uint4* gv = (const uint4*)(vtb + (((size_t)(bh*NBLK + kb)) << 12));
        __syncthreads();
        #pragma unroll
        for (int u=0;u<2;u++) {
            int idx = (u<<8) + tid;      // 0..511
            int r = idx>>3, c = (idx&7)<<3;
            *(uint4*)&Ks[r][c] = gk[idx];
            *(uint4*)&Vt[r][c] = gv[idx];
        }
        __syncthreads();

        // S^T = K @ Q^T : lane holds q-col=qc, keys 16m+4g+{0..3}
        f32x4 sf[4];
        #pragma unroll
        for (int m=0;m<4;m++) sf[m] = (f32x4){0.f,0.f,0.f,0.f};
        #pragma unroll
        for (int ks=0;ks<2;ks++)
            #pragma unroll
            for (int m=0;m<4;m++) {
                bf16x8 ak = *(const bf16x8*)&Ks[(m<<4)+qc][(ks<<5)+(g<<3)];
                sf[m] = __builtin_amdgcn_mfma_f32_16x16x32_bf16(ak, bq[ks], sf[m], 0, 0, 0);
            }

        float s[16];
        float bmax = -INFINITY;
        #pragma unroll
        for (int m=0;m<4;m++)
            #pragma unroll
            for (int r2=0;r2<4;r2++) {
                const int kl = (m<<4)+(g<<2)+r2;
                float v = sf[m][r2]*0.125f;
                if (isdiag && kl > qib) v = -1e30f;
                s[(m<<2)+r2] = v;
                bmax = fmaxf(bmax, v);
            }
        bmax = fmaxf(bmax, __shfl_xor(bmax, 16));
        bmax = fmaxf(bmax, __shfl_xor(bmax, 32));
        const float mnew = fmaxf(mrun, bmax);
        const float cf = __expf(mrun - mnew);
        float ls = 0.f;
        #pragma unroll
        for (int m=0;m<4;m++) {
            float p0 = __expf(s[(m<<2)+0]-mnew);
            float p1 = __expf(s[(m<<2)+1]-mnew);
            float p2 = __expf(s[(m<<2)+2]-mnew);
            float p3 = __expf(s[(m<<2)+3]-mnew);
            ls += p0+p1+p2+p3;
            const int koff = (m<<4)+(g<<2);
            *(unsigned int*)&Pl[wave][qc][koff]   = pack2(p0,p1);
            *(unsigned int*)&Pl[wave][qc][koff+2] = pack2(p2,p3);
        }
        ls += __shfl_xor(ls, 16);
        ls += __shfl_xor(ls, 32);
        lrun = lrun*cf + ls;
        cfl[wave][qc] = cf;
        // rescale O rows (lane's O-rows are 4g+r, need cf of those rows)
        f32x4 cf4 = *(const f32x4*)&cfl[wave][g<<2];
        #pragma unroll
        for (int n=0;n<4;n++) oacc[n] *= cf4;
        // O += P @ V  (A = P from LDS, B = V^T rows from LDS)
        #pragma unroll
        for (int ks=0;ks<2;ks++) {
            bf16x8 pa = *(const bf16x8*)&Pl[wave][qc][(ks<<5)+(g<<3)];
            #pragma unroll
            for (int n=0;n<4;n++) {
                bf16x8 vb = *(const bf16x8*)&Vt[(n<<4)+qc][(ks<<5)+(g<<3)];
                oacc[n] = __builtin_amdgcn_mfma_f32_16x16x32_bf16(pa, vb, oacc[n], 0, 0, 0);
            }
        }
        mrun = mnew;
    }

    f32x4 il4 = (f32x4){0.f,0.f,0.f,0.f};
    if (nproc) {
        lvl[wave][qc] = 1.0f / lrun;
        il4 = *(const f32x4*)&lvl[wave][g<<2];
    }
    #pragma unroll
    for (int n=0;n<4;n++)
        #pragma unroll
        for (int r2=0;r2<4;r2++) {
            float val = nproc ? oacc[n][r2]*il4[r2]
                              : vmeanp[(bh<<6)+(n<<4)+qc];
            const int row = (qb<<6) + (wave<<4) + (g<<2) + r2;
            attno[(((size_t)(b*S_+row))<<10) + (h<<6) + (n<<4) + qc] = f2bf(val);
        }
}

extern "C" void kernel_launch(void* const* d_in, const int* in_sizes, int n_in,
                              void* d_out, int out_size, void* d_ws, size_t ws_size,
                              hipStream_t stream) {
    (void)in_sizes; (void)n_in; (void)out_size; (void)ws_size;
    const float* x     = (const float*)d_in[0];
    const float* w_q   = (const float*)d_in[1];
    const float* w_kvd = (const float*)d_in[2];
    const float* w_kvu = (const float*)d_in[3];
    const float* w_o   = (const float*)d_in[4];
    const float* w_sc  = (const float*)d_in[5];
    float* out = (float*)d_out;

    char* p = (char*)d_ws;
    auto alloc = [&](size_t bytes) -> void* {
        void* r = (void*)p;
        p += (bytes + 255) & ~(size_t)255;
        return r;
    };
    float* cosT  = (float*)alloc((size_t)S_*HD_*4);
    float* sinT  = (float*)alloc((size_t)S_*HD_*4);
    unsigned short* qlinb = (unsigned short*)alloc((size_t)BS_*D_*2);   // reused as attnob
    unsigned short* kvb   = (unsigned short*)alloc((size_t)BS_*2*D_*2);
    unsigned short* xb    = (unsigned short*)alloc((size_t)BS_*D_*2);
    unsigned short* wqb   = (unsigned short*)alloc((size_t)D_*D_*2);
    unsigned short* wkdb  = (unsigned short*)alloc((size_t)R_*D_*2);
    unsigned short* wkub  = (unsigned short*)alloc((size_t)2*D_*R_*2);
    unsigned short* wob   = (unsigned short*)alloc((size_t)D_*D_*2);
    unsigned short* latb  = (unsigned short*)alloc((size_t)BS_*R_*2);
    unsigned short* qrb   = (unsigned short*)alloc((size_t)BS_*D_*2);
    unsigned short* krb   = (unsigned short*)alloc((size_t)BS_*D_*2);
    unsigned short* vrb   = (unsigned short*)alloc((size_t)BS_*D_*2);
    unsigned short* vtb   = (unsigned short*)alloc((size_t)BS_*D_*2);
    float* rows   = (float*)alloc((size_t)BS_*4);
    int*   sel    = (int*)  alloc((size_t)B_*TOPK_*4);
    float* vmeanp = (float*)alloc((size_t)B_*H_*HD_*4);
    unsigned short* attnob = qlinb;     // qlinb dead after reorg2

    rope_tables_k<<<(S_*HD_+255)/256, 256, 0, stream>>>(cosT, sinT);
    cvt_bf16_k<<<(BS_*D_)/2048,   256, 0, stream>>>(x,     xb,   BS_*D_);
    cvt_bf16_k<<<(D_*D_)/2048,    256, 0, stream>>>(w_q,   wqb,  D_*D_);
    cvt_bf16_k<<<(R_*D_)/2048,    256, 0, stream>>>(w_kvd, wkdb, R_*D_);
    cvt_bf16_k<<<(2*D_*R_)/2048,  256, 0, stream>>>(w_kvu, wkub, 2*D_*R_);
    cvt_bf16_k<<<(D_*D_)/2048,    256, 0, stream>>>(w_o,   wob,  D_*D_);

    gemm_mfma_k<true><<<dim3(D_/64,   BS_/128), 256, 0, stream>>>(xb,   wqb,  qlinb, BS_, D_,   D_);
    gemm_mfma_k<true><<<dim3(R_/64,   BS_/128), 256, 0, stream>>>(xb,   wkdb, latb,  BS_, R_,   D_);
    gemm_mfma_k<true><<<dim3(2*D_/64, BS_/128), 256, 0, stream>>>(latb, wkub, kvb,   BS_, 2*D_, R_);

    rowscore_k<<<256, 256, 0, stream>>>(x, w_sc, rows);
    blocktopk_k<<<1, 256, 0, stream>>>(rows, sel);
    reorg2_k<<<(B_*H_*S_*HD_)/256, 256, 0, stream>>>(qlinb, kvb, cosT, sinT, qrb, krb, vrb);
    vt_k<<<B_*H_*NBLK, 256, 0, stream>>>(vrb, vtb);
    vmean_k<<<B_*H_, 256, 0, stream>>>(vrb, vmeanp);
    attn_mfma_k<<<B_*H_*NBLK, 256, 0, stream>>>(qrb, krb, vtb, sel, vmeanp, attnob);
    gemm_mfma_k<false><<<dim3(D_/64, BS_/128), 256, 0, stream>>>(attnob, wob, out, BS_, D_, D_);
}

// Round 6
// 160.168 us; speedup vs baseline: 5.8420x; 1.2644x over previous
//
#include <hip/hip_runtime.h>
#include <hip/hip_bf16.h>
#include <math.h>

#define B_ 2
#define S_ 2048
#define D_ 1024
#define H_ 16
#define HD_ 64
#define R_ 128
#define NBLK 32
#define TOPK_ 4
#define BS_ (B_*S_)

typedef __attribute__((ext_vector_type(8))) short bf16x8;
typedef __attribute__((ext_vector_type(4))) float f32x4;

__device__ __forceinline__ unsigned short f2bf(float f) {
    unsigned int u = __float_as_uint(f);
    u += 0x7fffu + ((u >> 16) & 1u);
    return (unsigned short)(u >> 16);
}
__device__ __forceinline__ float bf2f(unsigned short h) {
    return __uint_as_float(((unsigned int)h) << 16);
}
__device__ __forceinline__ unsigned int pack2(float a, float b) {
    return (unsigned int)f2bf(a) | ((unsigned int)f2bf(b) << 16);
}
__device__ __forceinline__ void gload_lds16(const void* g, void* l) {
    __builtin_amdgcn_global_load_lds((const __attribute__((address_space(1))) void*)g,
                                     (__attribute__((address_space(3))) void*)l, 16, 0, 0);
}

// ---------------- RoPE tables ----------------
__global__ void rope_tables_k(float* __restrict__ cosT, float* __restrict__ sinT) {
    int idx = blockIdx.x*256 + threadIdx.x;
    if (idx >= S_*HD_) return;
    int s  = idx >> 6;
    int hd = idx & 63;
    int j = (hd < 32) ? hd : hd - 32;
    float inv = powf(100000.0f, -((float)(2*j) / 64.0f));
    float fr = (float)s * inv;
    cosT[idx] = cosf(fr);
    sinT[idx] = sinf(fr);
}

// ---------------- segmented weight cvt: w_q|w_kvd -> wcat, w_kvu -> wkub, w_o -> wob ----------------
__global__ __launch_bounds__(256) void cvtw_k(const float* __restrict__ wq,
        const float* __restrict__ wkd, const float* __restrict__ wku,
        const float* __restrict__ wo, unsigned short* __restrict__ wcat,
        unsigned short* __restrict__ wkub, unsigned short* __restrict__ wob) {
    const int blk = blockIdx.x;
    const float* src; unsigned short* dst; int base;
    if      (blk < 512) { src = wq;  dst = wcat;            base = blk;       }
    else if (blk < 576) { src = wkd; dst = wcat + 1048576;  base = blk - 512; }
    else if (blk < 704) { src = wku; dst = wkub;            base = blk - 576; }
    else                { src = wo;  dst = wob;             base = blk - 704; }
    const int i = base*2048 + threadIdx.x*8;
    float4 a = *(const float4*)&src[i];
    float4 b = *(const float4*)&src[i+4];
    uint4 o;
    o.x = pack2(a.x, a.y); o.y = pack2(a.z, a.w);
    o.z = pack2(b.x, b.y); o.w = pack2(b.z, b.w);
    *(uint4*)&dst[i] = o;
}

// ---------------- MFMA GEMM C = A @ B^T, 128x64 tile, BK=64, fused epilogues ----------------
// EPI 0: plain fp32 out (o0). EPI 1: cols<1024 -> RoPE -> qrb(o0), else latb(o1).
// EPI 2: cols<1024 -> RoPE -> krb(o0), else vrb(o1).  [B,H,S,HD] layouts.
template<int EPI>
__global__ __launch_bounds__(256) void gemm_mfma_k(const unsigned short* __restrict__ A,
        const unsigned short* __restrict__ Bm, int M, int N, int K,
        void* __restrict__ o0, void* __restrict__ o1,
        const float* __restrict__ cosT, const float* __restrict__ sinT) {
    __shared__ unsigned short As[128*64];
    __shared__ unsigned short Bs[64*64];
    const int tid  = threadIdx.x;
    const int wave = tid >> 6, lane = tid & 63;
    const int bm = blockIdx.y << 7, bn = blockIdx.x << 6;
    const int g  = lane >> 4, qc = lane & 15;
    const int srow  = lane >> 3;             // row within 8-row chunk
    const int sslot = (lane & 7) ^ srow;     // inverse-swizzled global 16B slot

    f32x4 acc[2][4];
    #pragma unroll
    for (int m=0;m<2;m++)
        #pragma unroll
        for (int n=0;n<4;n++)
            acc[m][n] = (f32x4){0.f,0.f,0.f,0.f};

    for (int k0 = 0; k0 < K; k0 += 64) {
        __syncthreads();
        #pragma unroll
        for (int it = 0; it < 4; ++it) {
            const int chunk = (it << 2) | wave;       // 0..15
            const int row   = (chunk << 3) | srow;    // 0..127
            gload_lds16(A + (size_t)(bm + row) * K + k0 + (sslot << 3), &As[chunk << 9]);
        }
        #pragma unroll
        for (int it = 0; it < 2; ++it) {
            const int chunk = (it << 2) | wave;       // 0..7
            const int row   = (chunk << 3) | srow;    // 0..63
            gload_lds16(Bm + (size_t)(bn + row) * K + k0 + (sslot << 3), &Bs[chunk << 9]);
        }
        __syncthreads();
        #pragma unroll
        for (int ks = 0; ks < 2; ++ks) {
            const int swb = ((ks << 2) | g) ^ (lane & 7);  // swizzled read slot
            bf16x8 af[2], bfr[4];
            #pragma unroll
            for (int m = 0; m < 2; ++m)
                af[m]  = *(const bf16x8*)&As[(((wave << 5) + (m << 4) + qc) << 6) + (swb << 3)];
            #pragma unroll
            for (int n = 0; n < 4; ++n)
                bfr[n] = *(const bf16x8*)&Bs[(((n << 4) + qc) << 6) + (swb << 3)];
            #pragma unroll
            for (int m = 0; m < 2; ++m)
                #pragma unroll
                for (int n = 0; n < 4; ++n)
                    acc[m][n] = __builtin_amdgcn_mfma_f32_16x16x32_bf16(af[m], bfr[n], acc[m][n], 0, 0, 0);
        }
    }

    if (EPI == 0) {
        float* C = (float*)o0;
        #pragma unroll
        for (int m = 0; m < 2; ++m) {
            const int r0 = bm + (wave << 5) + (m << 4) + (g << 2);
            #pragma unroll
            for (int n = 0; n < 4; ++n) {
                const int c = bn + (n << 4) + qc;
                #pragma unroll
                for (int j = 0; j < 4; ++j)
                    C[(size_t)(r0 + j) * N + c] = acc[m][n][j];
            }
        }
    } else {
        const bool isrope = (bn < 1024);
        if (isrope) {
            const int h = bn >> 6;
            unsigned short* dst = (unsigned short*)o0;   // qrb or krb
            #pragma unroll
            for (int m = 0; m < 2; ++m) {
                const int r0 = bm + (wave << 5) + (m << 4) + (g << 2);
                #pragma unroll
                for (int j = 0; j < 4; ++j) {
                    const int row = r0 + j;
                    const int b = row >> 11, s = row & (S_-1);
                    const size_t obase = ((size_t)(b*H_ + h) * S_ + s) << 6;
                    #pragma unroll
                    for (int n = 0; n < 4; ++n) {
                        const int hd = (n << 4) + qc;
                        const float c_ = cosT[(s << 6) + hd];
                        const float sn = sinT[(s << 6) + hd];
                        const float rot = (n < 2) ? -acc[m][n ^ 2][j] : acc[m][n ^ 2][j];
                        dst[obase + hd] = f2bf(acc[m][n][j] * c_ + rot * sn);
                    }
                }
            }
        } else if (EPI == 1) {         // latent columns 1024..1151
            unsigned short* latb = (unsigned short*)o1;
            const int c0 = bn - 1024;
            #pragma unroll
            for (int m = 0; m < 2; ++m) {
                const int r0 = bm + (wave << 5) + (m << 4) + (g << 2);
                #pragma unroll
                for (int n = 0; n < 4; ++n) {
                    const int c = c0 + (n << 4) + qc;
                    #pragma unroll
                    for (int j = 0; j < 4; ++j)
                        latb[(size_t)(r0 + j) * R_ + c] = f2bf(acc[m][n][j]);
                }
            }
        } else {                        // EPI==2, v columns 1024..2047
            const int h = (bn >> 6) - 16;
            unsigned short* vrb = (unsigned short*)o1;
            #pragma unroll
            for (int m = 0; m < 2; ++m) {
                const int r0 = bm + (wave << 5) + (m << 4) + (g << 2);
                #pragma unroll
                for (int j = 0; j < 4; ++j) {
                    const int row = r0 + j;
                    const int b = row >> 11, s = row & (S_-1);
                    const size_t obase = ((size_t)(b*H_ + h) * S_ + s) << 6;
                    #pragma unroll
                    for (int n = 0; n < 4; ++n)
                        vrb[obase + (n << 4) + qc] = f2bf(acc[m][n][j]);
                }
            }
        }
    }
}

// ---------------- row scores + x->bf16: one wave per 4 rows ----------------
__global__ __launch_bounds__(256) void rowscore_cvt_k(const float* __restrict__ x,
        const float* __restrict__ wsc, float* __restrict__ rows,
        unsigned short* __restrict__ xb) {
    const int wid  = (blockIdx.x << 2) + (threadIdx.x >> 6);  // 0..1023
    const int lane = threadIdx.x & 63;
    #pragma unroll
    for (int r = 0; r < 4; ++r) {
        const int row = (wid << 2) + r;                        // 0..4095
        const float* xp = x + (size_t)row * D_;
        unsigned short* xo = xb + (size_t)row * D_;
        float acc = 0.f;
        #pragma unroll
        for (int j = 0; j < 4; ++j) {
            const int off = ((j << 6) + lane) << 2;            // coalesced float4
            float4 xv = *(const float4*)&xp[off];
            float4 wv = *(const float4*)&wsc[off];
            acc = fmaf(xv.x, wv.x, acc);
            acc = fmaf(xv.y, wv.y, acc);
            acc = fmaf(xv.z, wv.z, acc);
            acc = fmaf(xv.w, wv.w, acc);
            uint2 o; o.x = pack2(xv.x, xv.y); o.y = pack2(xv.z, xv.w);
            *(uint2*)&xo[off] = o;
        }
        #pragma unroll
        for (int m = 1; m <= 32; m <<= 1) acc += __shfl_xor(acc, m);
        if (lane == 0) rows[row] = acc;
    }
}

// ---------------- block sums + top-4 (strict > == lowest index on ties) ----------------
__global__ __launch_bounds__(256) void blocktopk_k(const float* __restrict__ rows,
        int* __restrict__ sel) {
    __shared__ float bs[64];
    const int bk = threadIdx.x >> 2, qt = threadIdx.x & 3;     // block 0..63, quarter
    const float* rp = rows + (bk << 6) + (qt << 4);
    float p = 0.f;
    #pragma unroll
    for (int i = 0; i < 16; ++i) p += rp[i];
    p += __shfl_xor(p, 1);
    p += __shfl_xor(p, 2);
    if (qt == 0) bs[bk] = p;
    __syncthreads();
    if (threadIdx.x < B_) {
        const int b = threadIdx.x;
        float sc[NBLK];
        for (int i = 0; i < NBLK; ++i) sc[i] = bs[b * NBLK + i];
        for (int j = 0; j < TOPK_; ++j) {
            float best = -INFINITY; int bi = 0;
            for (int i = 0; i < NBLK; ++i)
                if (sc[i] > best) { best = sc[i]; bi = i; }
            sel[b * TOPK_ + j] = bi;
            sc[bi] = -INFINITY;
        }
    }
}

// ---------------- V transpose per 64-block + vmean atomic accumulation ----------------
__global__ __launch_bounds__(256) void vt_k(const unsigned short* __restrict__ vrb,
        unsigned short* __restrict__ vtb, float* __restrict__ vsum) {
    const int wg = blockIdx.x;    // bh*NBLK + kb
    const int bh = wg >> 5;
    __shared__ unsigned short T[64][72];
    const uint4* src = (const uint4*)(vrb + (size_t)wg*4096);
    #pragma unroll
    for (int u=0;u<2;u++) {
        int idx = (u<<8) + threadIdx.x;   // 0..511
        int r = idx>>3, c = (idx&7)<<3;
        *(uint4*)&T[r][c] = src[idx];
    }
    __syncthreads();
    unsigned short* dst = vtb + (size_t)wg*4096;
    #pragma unroll
    for (int u=0;u<2;u++) {
        int idx = (u<<8) + threadIdx.x;
        int dd = idx>>3, k0 = (idx&7)<<3;
        unsigned short tmp[8];
        float sm = 0.f;
        #pragma unroll
        for (int j=0;j<8;j++) { tmp[j] = T[k0+j][dd]; sm += bf2f(tmp[j]); }
        *(uint4*)&dst[(size_t)idx<<3] = *(uint4*)tmp;   // dst[dd*64 + k0]
        sm += __shfl_xor(sm, 1);
        sm += __shfl_xor(sm, 2);
        sm += __shfl_xor(sm, 4);
        if ((threadIdx.x & 7) == 0) atomicAdd(&vsum[(bh<<6)+dd], sm);
    }
}

// ---------------- MFMA block-sparse attention: wg=(b,h,qb), 4 waves x 16 q-rows ----------------
__global__ __launch_bounds__(256) void attn_mfma_k(const unsigned short* __restrict__ qrb,
        const unsigned short* __restrict__ krb, const unsigned short* __restrict__ vtb,
        const int* __restrict__ sel, const float* __restrict__ vsum,
        unsigned short* __restrict__ attno) {
    const int qb = blockIdx.x & (NBLK-1);
    const int bh = blockIdx.x >> 5;
    const int b  = bh >> 4;
    const int h  = bh & 15;
    const int tid  = threadIdx.x;
    const int wave = tid >> 6, lane = tid & 63;
    const int g = lane >> 4, qc = lane & 15;

    __shared__ unsigned short Ks[64][72];      // [key][d]
    __shared__ unsigned short Vt[64][72];      // [d][key]
    __shared__ unsigned short Pl[4][16][72];   // per-wave P [q][key]
    __shared__ float cfl[4][16];
    __shared__ float lvl[4][16];

    int selb[4];
    #pragma unroll
    for (int j=0;j<4;j++) selb[j] = sel[(b<<2)+j];
    const bool diag = (selb[0]==qb)|(selb[1]==qb)|(selb[2]==qb)|(selb[3]==qb);

    // Q B-frags (per wave: rows qb*64 + wave*16 .. +16)
    const unsigned short* qp = qrb + (((size_t)bh*S_ + (qb<<6) + (wave<<4) + qc) << 6);
    bf16x8 bq[2];
    bq[0] = *(const bf16x8*)(qp + (g<<3));
    bq[1] = *(const bf16x8*)(qp + 32 + (g<<3));

    f32x4 oacc[4];
    #pragma unroll
    for (int n=0;n<4;n++) oacc[n] = (f32x4){0.f,0.f,0.f,0.f};
    float mrun = -INFINITY, lrun = 0.f;
    int nproc = 0;
    const int qib = (wave<<4) + qc;   // this lane's q-row within the 64-block

    for (int j = 0; j < 5; ++j) {     // wg-uniform control flow
        int kb; bool isdiag;
        if (j < 4) { kb = selb[j]; isdiag = false; if (kb >= qb) continue; }
        else       { if (!diag) continue; kb = qb; isdiag = true; }
        nproc++;
        const uint4* gk = (const uint4*)(krb + (((size_t)bh*S_ + (kb<<6)) << 6));
        const uint4* gv = (const uint4*)(vtb + (((size_t)(bh*NBLK + kb)) << 12));
        __syncthreads();
        #pragma unroll
        for (int u=0;u<2;u++) {
            int idx = (u<<8) + tid;      // 0..511
            int r = idx>>3, c = (idx&7)<<3;
            *(uint4*)&Ks[r][c] = gk[idx];
            *(uint4*)&Vt[r][c] = gv[idx];
        }
        __syncthreads();

        // S^T = K @ Q^T : lane holds q-col=qc, keys 16m+4g+{0..3}
        f32x4 sf[4];
        #pragma unroll
        for (int m=0;m<4;m++) sf[m] = (f32x4){0.f,0.f,0.f,0.f};
        #pragma unroll
        for (int ks=0;ks<2;ks++)
            #pragma unroll
            for (int m=0;m<4;m++) {
                bf16x8 ak = *(const bf16x8*)&Ks[(m<<4)+qc][(ks<<5)+(g<<3)];
                sf[m] = __builtin_amdgcn_mfma_f32_16x16x32_bf16(ak, bq[ks], sf[m], 0, 0, 0);
            }

        float s[16];
        float bmax = -INFINITY;
        #pragma unroll
        for (int m=0;m<4;m++)
            #pragma unroll
            for (int r2=0;r2<4;r2++) {
                const int kl = (m<<4)+(g<<2)+r2;
                float v = sf[m][r2]*0.125f;
                if (isdiag && kl > qib) v = -1e30f;
                s[(m<<2)+r2] = v;
                bmax = fmaxf(bmax, v);
            }
        bmax = fmaxf(bmax, __shfl_xor(bmax, 16));
        bmax = fmaxf(bmax, __shfl_xor(bmax, 32));
        const float mnew = fmaxf(mrun, bmax);
        const float cf = __expf(mrun - mnew);
        float ls = 0.f;
        #pragma unroll
        for (int m=0;m<4;m++) {
            float p0 = __expf(s[(m<<2)+0]-mnew);
            float p1 = __expf(s[(m<<2)+1]-mnew);
            float p2 = __expf(s[(m<<2)+2]-mnew);
            float p3 = __expf(s[(m<<2)+3]-mnew);
            ls += p0+p1+p2+p3;
            const int koff = (m<<4)+(g<<2);
            *(unsigned int*)&Pl[wave][qc][koff]   = pack2(p0,p1);
            *(unsigned int*)&Pl[wave][qc][koff+2] = pack2(p2,p3);
        }
        ls += __shfl_xor(ls, 16);
        ls += __shfl_xor(ls, 32);
        lrun = lrun*cf + ls;
        cfl[wave][qc] = cf;
        // rescale O rows (lane's O-rows are 4g+r, need cf of those rows)
        f32x4 cf4 = *(const f32x4*)&cfl[wave][g<<2];
        #pragma unroll
        for (int n=0;n<4;n++) oacc[n] *= cf4;
        // O += P @ V  (A = P from LDS, B = V^T rows from LDS)
        #pragma unroll
        for (int ks=0;ks<2;ks++) {
            bf16x8 pa = *(const bf16x8*)&Pl[wave][qc][(ks<<5)+(g<<3)];
            #pragma unroll
            for (int n=0;n<4;n++) {
                bf16x8 vb = *(const bf16x8*)&Vt[(n<<4)+qc][(ks<<5)+(g<<3)];
                oacc[n] = __builtin_amdgcn_mfma_f32_16x16x32_bf16(pa, vb, oacc[n], 0, 0, 0);
            }
        }
        mrun = mnew;
    }

    f32x4 il4 = (f32x4){0.f,0.f,0.f,0.f};
    if (nproc) {
        lvl[wave][qc] = 1.0f / lrun;
        il4 = *(const f32x4*)&lvl[wave][g<<2];
    }
    #pragma unroll
    for (int n=0;n<4;n++)
        #pragma unroll
        for (int r2=0;r2<4;r2++) {
            float val = nproc ? oacc[n][r2]*il4[r2]
                              : vsum[(bh<<6)+(n<<4)+qc] * (1.0f/(float)S_);
            const int row = (qb<<6) + (wave<<4) + (g<<2) + r2;
            attno[(((size_t)(b*S_+row))<<10) + (h<<6) + (n<<4) + qc] = f2bf(val);
        }
}

extern "C" void kernel_launch(void* const* d_in, const int* in_sizes, int n_in,
                              void* d_out, int out_size, void* d_ws, size_t ws_size,
                              hipStream_t stream) {
    (void)in_sizes; (void)n_in; (void)out_size; (void)ws_size;
    const float* x     = (const float*)d_in[0];
    const float* w_q   = (const float*)d_in[1];
    const float* w_kvd = (const float*)d_in[2];
    const float* w_kvu = (const float*)d_in[3];
    const float* w_o   = (const float*)d_in[4];
    const float* w_sc  = (const float*)d_in[5];
    float* out = (float*)d_out;

    char* p = (char*)d_ws;
    auto alloc = [&](size_t bytes) -> void* {
        void* r = (void*)p;
        p += (bytes + 255) & ~(size_t)255;
        return r;
    };
    float* cosT  = (float*)alloc((size_t)S_*HD_*4);
    float* sinT  = (float*)alloc((size_t)S_*HD_*4);
    unsigned short* xb    = (unsigned short*)alloc((size_t)BS_*D_*2);
    unsigned short* wcat  = (unsigned short*)alloc((size_t)(D_+R_)*D_*2);   // w_q ; w_kvd
    unsigned short* wkub  = (unsigned short*)alloc((size_t)2*D_*R_*2);
    unsigned short* wob   = (unsigned short*)alloc((size_t)D_*D_*2);
    unsigned short* latb  = (unsigned short*)alloc((size_t)BS_*R_*2);
    unsigned short* qrb   = (unsigned short*)alloc((size_t)BS_*D_*2);
    unsigned short* krb   = (unsigned short*)alloc((size_t)BS_*D_*2);
    unsigned short* vrb   = (unsigned short*)alloc((size_t)BS_*D_*2);
    unsigned short* vtb   = (unsigned short*)alloc((size_t)BS_*D_*2);
    unsigned short* attnob= (unsigned short*)alloc((size_t)BS_*D_*2);
    float* rows   = (float*)alloc((size_t)BS_*4);
    int*   sel    = (int*)  alloc((size_t)B_*TOPK_*4);
    float* vsum   = (float*)alloc((size_t)B_*H_*HD_*4);

    rope_tables_k<<<(S_*HD_+255)/256, 256, 0, stream>>>(cosT, sinT);
    cvtw_k<<<1216, 256, 0, stream>>>(w_q, w_kvd, w_kvu, w_o, wcat, wkub, wob);
    rowscore_cvt_k<<<256, 256, 0, stream>>>(x, w_sc, rows, xb);
    blocktopk_k<<<1, 256, 0, stream>>>(rows, sel);

    // q-proj + kv-down fused (N = 1024 + 128), RoPE'd q -> qrb, latent -> latb
    gemm_mfma_k<1><<<dim3((D_+R_)/64, BS_/128), 256, 0, stream>>>(
        xb, wcat, BS_, D_+R_, D_, qrb, latb, cosT, sinT);
    // kv-up: RoPE'd k -> krb, v -> vrb
    gemm_mfma_k<2><<<dim3(2*D_/64, BS_/128), 256, 0, stream>>>(
        latb, wkub, BS_, 2*D_, R_, krb, vrb, cosT, sinT);

    hipMemsetAsync(vsum, 0, (size_t)B_*H_*HD_*4, stream);
    vt_k<<<B_*H_*NBLK, 256, 0, stream>>>(vrb, vtb, vsum);
    attn_mfma_k<<<B_*H_*NBLK, 256, 0, stream>>>(qrb, krb, vtb, sel, vsum, attnob);
    gemm_mfma_k<0><<<dim3(D_/64, BS_/128), 256, 0, stream>>>(
        attnob, wob, BS_, D_, D_, out, nullptr, nullptr, nullptr);
}